// Round 6
// baseline (411.420 us; speedup 1.0000x reference)
//
#include <hip/hip_runtime.h>
#include <cstdint>

typedef unsigned short u16;
typedef unsigned char u8;
typedef __attribute__((ext_vector_type(8))) __bf16 bf16x8;
typedef __attribute__((ext_vector_type(4))) float f32x4;

#define MFMA16(a, b, c) __builtin_amdgcn_mfma_f32_16x16x32_bf16((a), (b), (c), 0, 0, 0)

__device__ __forceinline__ u16 f2b(float f) {            // SW RNE (prep kernels only)
    union { float f; unsigned u; } v; v.f = f;
    unsigned r = v.u + 0x7fffu + ((v.u >> 16) & 1u);
    return (u16)(r >> 16);
}
__device__ __forceinline__ u16 f2b_hw(float f) {         // HW cvt (hot path)
    union { __bf16 h; u16 u; } cv; cv.h = (__bf16)f; return cv.u;
}
__device__ __forceinline__ float b2f(u16 h) {
    union { unsigned u; float f; } v; v.u = ((unsigned)h) << 16; return v.f;
}
__device__ __forceinline__ float fast_rcp(float x) { return __builtin_amdgcn_rcpf(x); }
// mish(x) = x * tanh(softplus(x)) = x * (u^2-1)/(u^2+1), u = 1+e^x
__device__ __forceinline__ float mish_f(float x) {
    float e = __expf(fminf(x, 40.0f));
    float u = 1.0f + e;
    float u2 = u * u;
    return x * (u2 - 1.0f) * fast_rcp(u2 + 1.0f);
}
__device__ __forceinline__ float tanh_f(float y) {
    float e = __expf(2.0f * y);
    return 1.0f - 2.0f * fast_rcp(e + 1.0f);
}
__device__ __forceinline__ float sigmoid_f(float y) {
    return fast_rcp(1.0f + __expf(-y));
}
__device__ __forceinline__ float splus(float w) { return log1pf(__expf(w)); }

// ---------------- workspace layout (bytes) ----------------
#define WS_PERM      0u           // int[262144]
#define WS_GSC       1048576u     // int[16]
#define WS_GOFF      1048640u     // int[16]
#define WS_BBAND     1048704u     // int[4112]
#define WS_BSTART    1065152u     // int[4112]
#define WS_BNROWS    1081600u     // int[4112]
#define WS_SP        1098048u     // float[32]
#define WS_GPART     1098176u     // int[512*9]
#define WS_BANDS     1116608u     // u8[262144] band per row (k_scatter sidecar)
#define WS_W1P       1378752u     // u16[512*32]   [n][k]
#define WS_W2F       1411520u     // u16[256*512]  fragment-major NT=16 KB=16
#define WS_HW1F      1673664u     // u16[9*128*256] fragment-major per band NT=8 KB=8
#define WS_SWF       2263488u     // u16[64*256]   fragment-major NT=4 KB=8
#define WS_STWF      2296256u     // u16[64*256]
#define WS_NEEDED    2329024u

#define PACK_BLOCKS  512

// Fragment-major (FM): tile (nt,kb) -> 1KB block FMbase+((nt*KB+kb)*64+lane)*8,
// lane=(quad*16+l15) holds W[nt*16+l15][kb*32+quad*8+j]. One wave B-load = one
// contiguous coalesced 1KB transaction.

// ---------------- weight packing + band histogram + band sidecar ----------------
__global__ void k_pack(const float* __restrict__ x, int B,
                       const float* __restrict__ tw1, const float* __restrict__ tw2,
                       const float* __restrict__ hw1,
                       const float* __restrict__ sw1, const float* __restrict__ stw1,
                       const float* __restrict__ sun_w1, const float* __restrict__ sun_w2,
                       const float* __restrict__ storm_w1, const float* __restrict__ storm_w2,
                       u16* __restrict__ W1p, u16* __restrict__ W2f, u16* __restrict__ HWf,
                       u16* __restrict__ SWf, u16* __restrict__ STWf,
                       float* __restrict__ sp, int* __restrict__ gpart,
                       u8* __restrict__ bands)
{
    __shared__ int h[9];
    int ltid = threadIdx.x;
    int tid = blockIdx.x * blockDim.x + ltid;
    if (ltid < 9) h[ltid] = 0;
    __syncthreads();
    for (int i = tid; i < B; i += PACK_BLOCKS * 256) {
        int b = (int)x[i * 18 + 17];
        bands[i] = (u8)b;
        atomicAdd(&h[b], 1);
    }

    if (tid < 32) {
        const float* srcs[4] = { sun_w1, sun_w2, storm_w1, storm_w2 };
        float w = srcs[tid >> 3][tid & 7];
        sp[tid] = splus(w);
    }
    const int total = 16384 + 131072 + 294912 + 16384 + 16384;
    for (int i = tid; i < total; i += PACK_BLOCKS * 256) {
        int idx = i;
        if (idx < 16384) {                         // W1p[n][k] : 512 x 32 (k>=15 zero)
            int n = idx >> 5, k = idx & 31;
            W1p[idx] = (k < 15) ? f2b(tw1[k * 512 + n]) : (u16)0;
        } else if ((idx -= 16384) < 131072) {      // W2f: FM NT=16 KB=16
            int tile = idx >> 9, within = idx & 511;
            int lane = within >> 3, j = within & 7;
            int nt = tile >> 4, kb = tile & 15;
            int n = nt * 16 + (lane & 15);
            int k = kb * 32 + (lane >> 4) * 8 + j;
            W2f[idx] = f2b(tw2[k * 256 + n]);
        } else if ((idx -= 131072) < 294912) {     // HWf: per band g, FM NT=8 KB=8
            int g = idx >> 15, r = idx & 32767;
            int tile = r >> 9, within = r & 511;
            int lane = within >> 3, j = within & 7;
            int nt = tile >> 3, kb = tile & 7;
            int n = nt * 16 + (lane & 15);
            int k = kb * 32 + (lane >> 4) * 8 + j;
            HWf[idx] = f2b(hw1[(g * 256 + k) * 128 + n]);
        } else if ((idx -= 294912) < 16384) {      // SWf: FM NT=4 KB=8
            int tile = idx >> 9, within = idx & 511;
            int lane = within >> 3, j = within & 7;
            int nt = tile >> 3, kb = tile & 7;
            int n = nt * 16 + (lane & 15);
            int k = kb * 32 + (lane >> 4) * 8 + j;
            SWf[idx] = f2b(sw1[k * 64 + n]);
        } else {                                   // STWf
            idx -= 16384;
            int tile = idx >> 9, within = idx & 511;
            int lane = within >> 3, j = within & 7;
            int nt = tile >> 3, kb = tile & 7;
            int n = nt * 16 + (lane & 15);
            int k = kb * 32 + (lane >> 4) * 8 + j;
            STWf[idx] = f2b(stw1[k * 64 + n]);
        }
    }
    __syncthreads();
    if (ltid < 9) gpart[blockIdx.x * 9 + ltid] = h[ltid];
}

// ---------------- sum partials, group offsets + per-block table ----------------
__global__ void k_table(const int* __restrict__ gpart, int* __restrict__ goff,
                        int* __restrict__ gsc, int* __restrict__ blk_band,
                        int* __restrict__ blk_start, int* __restrict__ blk_nrows, int nblk_max)
{
    __shared__ int s_goff[10], s_bstart[10], s_cnt[9];
    int tid = threadIdx.x;
    if (tid < 9) {
        int s = 0;
        for (int b = 0; b < PACK_BLOCKS; ++b) s += gpart[b * 9 + tid];
        s_cnt[tid] = s;
    }
    __syncthreads();
    if (tid == 0) {
        int off = 0, boff = 0;
        for (int g = 0; g < 9; ++g) {
            s_goff[g] = off; goff[g] = off;
            s_bstart[g] = boff;
            off += s_cnt[g];
            boff += (s_cnt[g] + 63) >> 6;
        }
        s_goff[9] = off; goff[9] = off;
        s_bstart[9] = boff;
        for (int g = 0; g < 9; ++g) gsc[g] = 0;
    }
    __syncthreads();
    for (int b = tid; b < nblk_max; b += blockDim.x) {
        int band = -1, loc = 0;
        for (int g = 0; g < 9; ++g)
            if (b >= s_bstart[g] && b < s_bstart[g + 1]) { band = g; loc = b - s_bstart[g]; }
        blk_band[b] = band;
        if (band >= 0) {
            blk_start[b] = s_goff[band] + loc * 64;
            int rem = s_cnt[band] - loc * 64;
            blk_nrows[b] = rem < 64 ? rem : 64;
        } else { blk_start[b] = 0; blk_nrows[b] = 0; }
    }
}

// ---------------- counting-sort scatter (band sidecar: 0.26 MB vs 18 MB of x) ----------------
__global__ void k_scatter(const u8* __restrict__ bands, const int* __restrict__ goff,
                          int* __restrict__ gsc, int* __restrict__ perm, int B)
{
    __shared__ int wcnt[4][9];
    __shared__ int wpre[4][9];
    __shared__ int gbase[9];
    int tid = threadIdx.x;
    int lane = tid & 63, wave = tid >> 6;
    int i = blockIdx.x * blockDim.x + tid;
    int band = -1, rank = 0;
    if (i < B) band = (int)bands[i];
    for (int k = 0; k < 9; ++k) {
        unsigned long long m = __ballot(band == k);
        if (band == k) rank = __popcll(m & ((1ull << lane) - 1ull));
        if (lane == 0) wcnt[wave][k] = __popcll(m);
    }
    __syncthreads();
    if (tid < 9) {
        int k = tid, run = 0;
        for (int w = 0; w < 4; ++w) { wpre[w][k] = run; run += wcnt[w][k]; }
        gbase[k] = (run > 0) ? atomicAdd(&gsc[k], run) : 0;
    }
    __syncthreads();
    if (i < B && band >= 0) {
        int pos = goff[band] + gbase[band] + wpre[wave][band] + rank;
        perm[pos] = i;
    }
}

// ---------------- fused main kernel: 64 rows / block, 8 waves, uniform band ----------------
// __launch_bounds__(512,8): VGPR<=64 required for 8 waves/EU (m69: waves halve >64);
// LDS trimmed to <40KB (xA aliased with reduction scratch) -> 4 blocks/CU.
__global__ __launch_bounds__(512, 8) void k_main(
                       const float* __restrict__ x,
                       const int* __restrict__ perm,
                       const int* __restrict__ blk_band,
                       const int* __restrict__ blk_start,
                       const int* __restrict__ blk_nrows,
                       const u16* __restrict__ W1p, const u16* __restrict__ W2f,
                       const u16* __restrict__ HWf,
                       const u16* __restrict__ SWf, const u16* __restrict__ STWf,
                       const float* __restrict__ tb1, const float* __restrict__ tb2,
                       const float* __restrict__ hb1, const float* __restrict__ hw2,
                       const float* __restrict__ hb2,
                       const float* __restrict__ sb1, const float* __restrict__ sw2,
                       const float* __restrict__ sb2,
                       const float* __restrict__ stb1, const float* __restrict__ stw2,
                       const float* __restrict__ stb2,
                       const float* __restrict__ sp,
                       const float* __restrict__ sun_b1, const float* __restrict__ sun_b2,
                       const float* __restrict__ storm_b1, const float* __restrict__ storm_b2,
                       float* __restrict__ out)
{
    int bb = blk_band[blockIdx.x];
    if (bb < 0) return;
    int rstart = blk_start[blockIdx.x];
    int nrows  = blk_nrows[blockIdx.x];

    // xA dead after A-fragments load (pre-P1); reduction scratch live only in
    // epilogue -> alias (saves 4KB -> 4 blocks/CU).
    __shared__ union {
        u16 xA[64][32];        // 4096 B
        float red[16][64];     // [0:8)=head, [8:12)=sun, [12:16)=storm
    } su;
    __shared__ int rowsL[64];
    __shared__ float sfiL[64], kpL[64];
    __shared__ u16 buf[2][64][136];            // chunk dbuf; aliased as t[64][264]

    int tid = threadIdx.x;
    int lane = tid & 63, wave = tid >> 6;      // wave 0..7
    int quad = lane >> 4, l15 = lane & 15;

    if (tid < 64) {
        int r = rstart + (tid < nrows ? tid : 0);
        rowsL[tid] = perm[r];
    }
    for (int i = tid; i < 64 * 32; i += 512) ((u16*)su.xA)[i] = 0;
    __syncthreads();
    for (int i = tid; i < 64 * 18; i += 512) {
        int r = i / 18, c = i - r * 18;
        float v = x[rowsL[r] * 18 + c];
        if (c < 15) su.xA[r][c] = f2b_hw(v);
        else if (c == 15) sfiL[r] = v;
        else if (c == 16) kpL[r] = v;
    }
    __syncthreads();

    // A-fragments of x: A[m=mt*16+l15][k=quad*8+j]
    bf16x8 ax[4];
#pragma unroll
    for (int mt = 0; mt < 4; ++mt)
        ax[mt] = *(const bf16x8*)&su.xA[mt * 16 + l15][quad * 8];

    f32x4 acc2[2][4] = {};   // [ntl][mt], wave cols = wave*32 + ntl*16

    for (int c = 0; c < 4; ++c) {
        // ---- Phase 1: this wave's 16 cols of chunk c
        f32x4 acc1[4] = {};
        {
            int ncol = c * 128 + wave * 16 + l15;
            bf16x8 bw = *(const bf16x8*)&W1p[ncol * 32 + quad * 8];
#pragma unroll
            for (int mt = 0; mt < 4; ++mt)
                acc1[mt] = MFMA16(ax[mt], bw, acc1[mt]);
        }
        u16 (*bufc)[136] = buf[c & 1];
        {
            int ccol = wave * 16 + l15;
            float bias = tb1[c * 128 + ccol];
#pragma unroll
            for (int mt = 0; mt < 4; ++mt)
#pragma unroll
                for (int r = 0; r < 4; ++r)
                    bufc[mt * 16 + quad * 4 + r][ccol] = f2b_hw(mish_f(acc1[mt][r] + bias));
        }
        __syncthreads();
        // ---- Phase 2 partial: acc2 += chunk @ W2 (this wave's 32 cols), FM loads
        for (int ks = 0; ks < 4; ++ks) {
            bf16x8 a2[4];
#pragma unroll
            for (int mt = 0; mt < 4; ++mt)
                a2[mt] = *(const bf16x8*)&bufc[mt * 16 + l15][ks * 32 + quad * 8];
            int kb = c * 4 + ks;
#pragma unroll
            for (int ntl = 0; ntl < 2; ++ntl) {
                int nt = wave * 2 + ntl;
                bf16x8 bw = *(const bf16x8*)&W2f[((nt * 16 + kb) << 9) + lane * 8];
#pragma unroll
                for (int mt = 0; mt < 4; ++mt)
                    acc2[ntl][mt] = MFMA16(a2[mt], bw, acc2[ntl][mt]);
            }
        }
    }
    __syncthreads();   // all P2 reads of buf done before aliasing with t

    // ---- t = mish(acc2 + tb2) -> LDS t[64][264] (aliases buf)
    u16 (*tmat)[264] = (u16(*)[264])buf;
#pragma unroll
    for (int ntl = 0; ntl < 2; ++ntl) {
        int col = wave * 32 + ntl * 16 + l15;
        float bias = tb2[col];
#pragma unroll
        for (int mt = 0; mt < 4; ++mt)
#pragma unroll
            for (int r = 0; r < 4; ++r)
                tmat[mt * 16 + quad * 4 + r][col] = f2b_hw(mish_f(acc2[ntl][mt][r] + bias));
    }
    __syncthreads();

    // ---- Phase 3: head nt = wave; gates: waves 0-3 sun, 4-7 storm. K=256.
    f32x4 acch[4] = {}, accg[4] = {};
    const u16* Hw = HWf + bb * 32768;
    const u16* Gw = (wave < 4) ? SWf : STWf;
    int gnt = wave & 3;
    for (int kb = 0; kb < 8; ++kb) {
        bf16x8 a3[4];
#pragma unroll
        for (int mt = 0; mt < 4; ++mt)
            a3[mt] = *(const bf16x8*)&tmat[mt * 16 + l15][kb * 32 + quad * 8];
        bf16x8 bh = *(const bf16x8*)&Hw[((wave * 8 + kb) << 9) + lane * 8];
        bf16x8 bg = *(const bf16x8*)&Gw[((gnt * 8 + kb) << 9) + lane * 8];
#pragma unroll
        for (int mt = 0; mt < 4; ++mt) {
            acch[mt] = MFMA16(a3[mt], bh, acch[mt]);
            accg[mt] = MFMA16(a3[mt], bg, accg[mt]);
        }
    }

    // head epilogue: this wave's 16 cols, dot with hw2[band]
    float hsum[4][4];
    {
        int col = wave * 16 + l15;
        float hb = hb1[bb * 128 + col];
        float wv = hw2[bb * 128 + col];
#pragma unroll
        for (int mt = 0; mt < 4; ++mt)
#pragma unroll
            for (int r = 0; r < 4; ++r)
                hsum[mt][r] = mish_f(acch[mt][r] + hb) * wv;
    }
    // gate epilogue: this wave's 16 cols of sun or storm
    float gsum[4][4];
    {
        int n = gnt * 16 + l15;
        float gb = (wave < 4) ? sb1[n] : stb1[n];
        float gw = (wave < 4) ? sw2[n] : stw2[n];
#pragma unroll
        for (int mt = 0; mt < 4; ++mt)
#pragma unroll
            for (int r = 0; r < 4; ++r)
                gsum[mt][r] = mish_f(accg[mt][r] + gb) * gw;
    }
#pragma unroll
    for (int off = 1; off < 16; off <<= 1)
#pragma unroll
        for (int mt = 0; mt < 4; ++mt)
#pragma unroll
            for (int r = 0; r < 4; ++r) {
                hsum[mt][r] += __shfl_xor(hsum[mt][r], off, 64);
                gsum[mt][r] += __shfl_xor(gsum[mt][r], off, 64);
            }
    if (l15 == 0)
#pragma unroll
        for (int mt = 0; mt < 4; ++mt)
#pragma unroll
            for (int r = 0; r < 4; ++r) {
                int row = mt * 16 + quad * 4 + r;
                su.red[wave][row] = hsum[mt][r];
                su.red[8 + wave][row] = gsum[mt][r];   // waves 0-3 -> sun, 4-7 -> storm
            }
    __syncthreads();

    // ---- final scalar math per row (fp32 output)
    if (tid < 64 && tid < nrows) {
        int row = tid;
        float head = hb2[bb];
#pragma unroll
        for (int w = 0; w < 8; ++w) head += su.red[w][row];
        float sl = sb2[0], tl = stb2[0];
#pragma unroll
        for (int w = 0; w < 4; ++w) { sl += su.red[8 + w][row]; tl += su.red[12 + w][row]; }
        float sg = sigmoid_f(sl);
        float tg = sigmoid_f(tl);
        float v1 = sfiL[row], v2 = kpL[row];
        float sun_val = sun_b2[0], storm_val = storm_b2[0];
#pragma unroll
        for (int j = 0; j < 8; ++j) {
            sun_val   += tanh_f(v1 * sp[j]      + sun_b1[j])   * sp[8 + j];
            storm_val += tanh_f(v2 * sp[16 + j] + storm_b1[j]) * sp[24 + j];
        }
        out[rowsL[row]] = head + sg * sun_val + tg * storm_val;
    }
}

// ---------------- fallback: pure-VALU scalar kernel (used if ws too small) ----------------
__global__ __launch_bounds__(64) void k_simple(
    const float* __restrict__ x,
    const float* __restrict__ tw1, const float* __restrict__ tb1,
    const float* __restrict__ tw2, const float* __restrict__ tb2,
    const float* __restrict__ hw1, const float* __restrict__ hb1,
    const float* __restrict__ hw2, const float* __restrict__ hb2,
    const float* __restrict__ sw1, const float* __restrict__ sb1,
    const float* __restrict__ sw2, const float* __restrict__ sb2,
    const float* __restrict__ stw1, const float* __restrict__ stb1,
    const float* __restrict__ stw2, const float* __restrict__ stb2,
    const float* __restrict__ sun_w1, const float* __restrict__ sun_b1,
    const float* __restrict__ sun_w2, const float* __restrict__ sun_b2,
    const float* __restrict__ storm_w1, const float* __restrict__ storm_b1,
    const float* __restrict__ storm_w2, const float* __restrict__ storm_b2,
    float* __restrict__ out)
{
    __shared__ u16 t_lds[256 * 64];

    const int lane = threadIdx.x;
    const int r = blockIdx.x * 64 + lane;

    float xr[15];
#pragma unroll
    for (int k = 0; k < 15; ++k) xr[k] = x[r * 18 + k];
    const float sfi = x[r * 18 + 15];
    const float kp  = x[r * 18 + 16];
    const int band  = (int)x[r * 18 + 17];

    for (int tc = 0; tc < 4; ++tc) {
        float acc[64];
#pragma unroll
        for (int j = 0; j < 64; ++j) acc[j] = 0.0f;
        for (int n = 0; n < 512; ++n) {
            float p = tb1[n];
#pragma unroll
            for (int k = 0; k < 15; ++k) p += xr[k] * tw1[k * 512 + n];
            const float a1n = mish_f(p);
            const float* w2 = &tw2[n * 256 + tc * 64];
#pragma unroll
            for (int j = 0; j < 64; ++j) acc[j] += a1n * w2[j];
        }
#pragma unroll
        for (int j = 0; j < 64; ++j)
            t_lds[(tc * 64 + j) * 64 + lane] = f2b(mish_f(acc[j] + tb2[tc * 64 + j]));
    }
    __syncthreads();

    float head_val = 0.0f;
    for (int g = 0; g < 9; ++g) {
        float hs = 0.0f;
        for (int hc = 0; hc < 2; ++hc) {
            float pre[64];
#pragma unroll
            for (int j = 0; j < 64; ++j) pre[j] = 0.0f;
            for (int d = 0; d < 256; ++d) {
                const float td = b2f(t_lds[d * 64 + lane]);
                const float* wv = &hw1[g * 32768 + d * 128 + hc * 64];
#pragma unroll
                for (int j = 0; j < 64; ++j) pre[j] += td * wv[j];
            }
#pragma unroll
            for (int j = 0; j < 64; ++j) {
                const int h = hc * 64 + j;
                hs += mish_f(pre[j] + hb1[g * 128 + h]) * hw2[g * 128 + h];
            }
        }
        head_val += (band == g) ? (hs + hb2[g]) : 0.0f;
    }

    float pre_s[64], pre_t[64];
#pragma unroll
    for (int j = 0; j < 64; ++j) { pre_s[j] = 0.0f; pre_t[j] = 0.0f; }
    for (int d = 0; d < 256; ++d) {
        const float td = b2f(t_lds[d * 64 + lane]);
        const float* ws1 = &sw1[d * 64];
        const float* wt1 = &stw1[d * 64];
#pragma unroll
        for (int j = 0; j < 64; ++j) {
            pre_s[j] += td * ws1[j];
            pre_t[j] += td * wt1[j];
        }
    }
    float ls = sb2[0], lt = stb2[0];
#pragma unroll
    for (int j = 0; j < 64; ++j) {
        ls += mish_f(pre_s[j] + sb1[j]) * sw2[j];
        lt += mish_f(pre_t[j] + stb1[j]) * stw2[j];
    }
    const float sg = sigmoid_f(ls);
    const float tg = sigmoid_f(lt);

    float sun_val = sun_b2[0], storm_val = storm_b2[0];
#pragma unroll
    for (int j = 0; j < 8; ++j) {
        sun_val   += tanh_f(sfi * splus(sun_w1[j])  + sun_b1[j])   * splus(sun_w2[j]);
        storm_val += tanh_f(kp * splus(storm_w1[j]) + storm_b1[j]) * splus(storm_w2[j]);
    }

    out[r] = head_val + sg * sun_val + tg * storm_val;
}

extern "C" void kernel_launch(void* const* d_in, const int* in_sizes, int n_in,
                              void* d_out, int out_size, void* d_ws, size_t ws_size,
                              hipStream_t stream) {
    (void)n_in; (void)out_size;
    const float* x        = (const float*)d_in[0];
    const float* tw1      = (const float*)d_in[1];
    const float* tb1      = (const float*)d_in[2];
    const float* tw2      = (const float*)d_in[3];
    const float* tb2      = (const float*)d_in[4];
    const float* hw1      = (const float*)d_in[5];
    const float* hb1      = (const float*)d_in[6];
    const float* hw2      = (const float*)d_in[7];
    const float* hb2      = (const float*)d_in[8];
    const float* sw1      = (const float*)d_in[9];
    const float* sb1      = (const float*)d_in[10];
    const float* sw2      = (const float*)d_in[11];
    const float* sb2      = (const float*)d_in[12];
    const float* stw1     = (const float*)d_in[13];
    const float* stb1     = (const float*)d_in[14];
    const float* stw2     = (const float*)d_in[15];
    const float* stb2     = (const float*)d_in[16];
    const float* sun_w1   = (const float*)d_in[17];
    const float* sun_b1   = (const float*)d_in[18];
    const float* sun_w2   = (const float*)d_in[19];
    const float* sun_b2   = (const float*)d_in[20];
    const float* storm_w1 = (const float*)d_in[21];
    const float* storm_b1 = (const float*)d_in[22];
    const float* storm_w2 = (const float*)d_in[23];
    const float* storm_b2 = (const float*)d_in[24];

    const int B = in_sizes[0] / 18;

    if (ws_size < (size_t)WS_NEEDED) {
        k_simple<<<B / 64, 64, 0, stream>>>(x, tw1, tb1, tw2, tb2, hw1, hb1, hw2, hb2,
                                            sw1, sb1, sw2, sb2, stw1, stb1, stw2, stb2,
                                            sun_w1, sun_b1, sun_w2, sun_b2,
                                            storm_w1, storm_b1, storm_w2, storm_b2,
                                            (float*)d_out);
        return;
    }

    char* ws = (char*)d_ws;
    int*   perm      = (int*)(ws + WS_PERM);
    int*   gsc       = (int*)(ws + WS_GSC);
    int*   goff      = (int*)(ws + WS_GOFF);
    int*   blk_band  = (int*)(ws + WS_BBAND);
    int*   blk_start = (int*)(ws + WS_BSTART);
    int*   blk_nrows = (int*)(ws + WS_BNROWS);
    float* sp        = (float*)(ws + WS_SP);
    int*   gpart     = (int*)(ws + WS_GPART);
    u8*    bands     = (u8*)(ws + WS_BANDS);
    u16*   W1p       = (u16*)(ws + WS_W1P);
    u16*   W2f       = (u16*)(ws + WS_W2F);
    u16*   HWf       = (u16*)(ws + WS_HW1F);
    u16*   SWf       = (u16*)(ws + WS_SWF);
    u16*   STWf      = (u16*)(ws + WS_STWF);

    int nblk = B / 64 + 16;

    k_pack<<<PACK_BLOCKS, 256, 0, stream>>>(x, B, tw1, tw2, hw1, sw1, stw1,
                                            sun_w1, sun_w2, storm_w1, storm_w2,
                                            W1p, W2f, HWf, SWf, STWf, sp, gpart, bands);
    k_table<<<1, 256, 0, stream>>>(gpart, goff, gsc, blk_band, blk_start, blk_nrows, nblk);
    k_scatter<<<(B + 255) / 256, 256, 0, stream>>>(bands, goff, gsc, perm, B);
    k_main<<<nblk, 512, 0, stream>>>(x, perm, blk_band, blk_start, blk_nrows,
                                     W1p, W2f, HWf, SWf, STWf,
                                     tb1, tb2, hb1, hw2, hb2,
                                     sb1, sw2, sb2, stb1, stw2, stb2,
                                     sp, sun_b1, sun_b2, storm_b1, storm_b2,
                                     (float*)d_out);
}

// Round 7
// 342.221 us; speedup vs baseline: 1.2022x; 1.2022x over previous
//
#include <hip/hip_runtime.h>
#include <cstdint>

typedef unsigned short u16;
typedef unsigned char u8;
typedef __attribute__((ext_vector_type(8))) __bf16 bf16x8;
typedef __attribute__((ext_vector_type(4))) float f32x4;

#define MFMA16(a, b, c) __builtin_amdgcn_mfma_f32_16x16x32_bf16((a), (b), (c), 0, 0, 0)

__device__ __forceinline__ u16 f2b(float f) {            // SW RNE (prep kernels only)
    union { float f; unsigned u; } v; v.f = f;
    unsigned r = v.u + 0x7fffu + ((v.u >> 16) & 1u);
    return (u16)(r >> 16);
}
__device__ __forceinline__ u16 f2b_hw(float f) {         // HW cvt (hot path)
    union { __bf16 h; u16 u; } cv; cv.h = (__bf16)f; return cv.u;
}
__device__ __forceinline__ float b2f(u16 h) {
    union { unsigned u; float f; } v; v.u = ((unsigned)h) << 16; return v.f;
}
__device__ __forceinline__ float fast_rcp(float x) { return __builtin_amdgcn_rcpf(x); }
// mish(x) = x * tanh(softplus(x)) = x * (u^2-1)/(u^2+1), u = 1+e^x
__device__ __forceinline__ float mish_f(float x) {
    float e = __expf(fminf(x, 40.0f));
    float u = 1.0f + e;
    float u2 = u * u;
    return x * (u2 - 1.0f) * fast_rcp(u2 + 1.0f);
}
__device__ __forceinline__ float tanh_f(float y) {
    float e = __expf(2.0f * y);
    return 1.0f - 2.0f * fast_rcp(e + 1.0f);
}
__device__ __forceinline__ float sigmoid_f(float y) {
    return fast_rcp(1.0f + __expf(-y));
}
__device__ __forceinline__ float splus(float w) { return log1pf(__expf(w)); }

// ---------------- workspace layout (bytes) ----------------
#define WS_PERM      0u           // int[262144]
#define WS_GSC       1048576u     // int[16]
#define WS_GOFF      1048640u     // int[16]
#define WS_BBAND     1048704u     // int[4112]
#define WS_BSTART    1065152u     // int[4112]
#define WS_BNROWS    1081600u     // int[4112]
#define WS_SP        1098048u     // float[32]
#define WS_GPART     1098176u     // int[512*9]
#define WS_BANDS     1116608u     // u8[262144] band per row (k_scatter sidecar)
#define WS_W1P       1378752u     // u16[512*32]   [n][k]
#define WS_W2F       1411520u     // u16[256*512]  fragment-major NT=16 KB=16
#define WS_HW1F      1673664u     // u16[9*128*256] fragment-major per band NT=8 KB=8
#define WS_SWF       2263488u     // u16[64*256]   fragment-major NT=4 KB=8
#define WS_STWF      2296256u     // u16[64*256]
#define WS_NEEDED    2329024u

#define PACK_BLOCKS  512

// Fragment-major (FM): tile (nt,kb) -> 1KB block FMbase+((nt*KB+kb)*64+lane)*8,
// lane=(quad*16+l15) holds W[nt*16+l15][kb*32+quad*8+j]. One wave B-load = one
// contiguous coalesced 1KB transaction.

// ---------------- weight packing + band histogram + band sidecar ----------------
__global__ void k_pack(const float* __restrict__ x, int B,
                       const float* __restrict__ tw1, const float* __restrict__ tw2,
                       const float* __restrict__ hw1,
                       const float* __restrict__ sw1, const float* __restrict__ stw1,
                       const float* __restrict__ sun_w1, const float* __restrict__ sun_w2,
                       const float* __restrict__ storm_w1, const float* __restrict__ storm_w2,
                       u16* __restrict__ W1p, u16* __restrict__ W2f, u16* __restrict__ HWf,
                       u16* __restrict__ SWf, u16* __restrict__ STWf,
                       float* __restrict__ sp, int* __restrict__ gpart,
                       u8* __restrict__ bands)
{
    __shared__ int h[9];
    int ltid = threadIdx.x;
    int tid = blockIdx.x * blockDim.x + ltid;
    if (ltid < 9) h[ltid] = 0;
    __syncthreads();
    for (int i = tid; i < B; i += PACK_BLOCKS * 256) {
        int b = (int)x[i * 18 + 17];
        bands[i] = (u8)b;
        atomicAdd(&h[b], 1);
    }

    if (tid < 32) {
        const float* srcs[4] = { sun_w1, sun_w2, storm_w1, storm_w2 };
        float w = srcs[tid >> 3][tid & 7];
        sp[tid] = splus(w);
    }
    const int total = 16384 + 131072 + 294912 + 16384 + 16384;
    for (int i = tid; i < total; i += PACK_BLOCKS * 256) {
        int idx = i;
        if (idx < 16384) {                         // W1p[n][k] : 512 x 32 (k>=15 zero)
            int n = idx >> 5, k = idx & 31;
            W1p[idx] = (k < 15) ? f2b(tw1[k * 512 + n]) : (u16)0;
        } else if ((idx -= 16384) < 131072) {      // W2f: FM NT=16 KB=16
            int tile = idx >> 9, within = idx & 511;
            int lane = within >> 3, j = within & 7;
            int nt = tile >> 4, kb = tile & 15;
            int n = nt * 16 + (lane & 15);
            int k = kb * 32 + (lane >> 4) * 8 + j;
            W2f[idx] = f2b(tw2[k * 256 + n]);
        } else if ((idx -= 131072) < 294912) {     // HWf: per band g, FM NT=8 KB=8
            int g = idx >> 15, r = idx & 32767;
            int tile = r >> 9, within = r & 511;
            int lane = within >> 3, j = within & 7;
            int nt = tile >> 3, kb = tile & 7;
            int n = nt * 16 + (lane & 15);
            int k = kb * 32 + (lane >> 4) * 8 + j;
            HWf[idx] = f2b(hw1[(g * 256 + k) * 128 + n]);
        } else if ((idx -= 294912) < 16384) {      // SWf: FM NT=4 KB=8
            int tile = idx >> 9, within = idx & 511;
            int lane = within >> 3, j = within & 7;
            int nt = tile >> 3, kb = tile & 7;
            int n = nt * 16 + (lane & 15);
            int k = kb * 32 + (lane >> 4) * 8 + j;
            SWf[idx] = f2b(sw1[k * 64 + n]);
        } else {                                   // STWf
            idx -= 16384;
            int tile = idx >> 9, within = idx & 511;
            int lane = within >> 3, j = within & 7;
            int nt = tile >> 3, kb = tile & 7;
            int n = nt * 16 + (lane & 15);
            int k = kb * 32 + (lane >> 4) * 8 + j;
            STWf[idx] = f2b(stw1[k * 64 + n]);
        }
    }
    __syncthreads();
    if (ltid < 9) gpart[blockIdx.x * 9 + ltid] = h[ltid];
}

// ---------------- sum partials, group offsets + per-block table ----------------
__global__ void k_table(const int* __restrict__ gpart, int* __restrict__ goff,
                        int* __restrict__ gsc, int* __restrict__ blk_band,
                        int* __restrict__ blk_start, int* __restrict__ blk_nrows, int nblk_max)
{
    __shared__ int s_goff[10], s_bstart[10], s_cnt[9];
    int tid = threadIdx.x;
    if (tid < 9) {
        int s = 0;
        for (int b = 0; b < PACK_BLOCKS; ++b) s += gpart[b * 9 + tid];
        s_cnt[tid] = s;
    }
    __syncthreads();
    if (tid == 0) {
        int off = 0, boff = 0;
        for (int g = 0; g < 9; ++g) {
            s_goff[g] = off; goff[g] = off;
            s_bstart[g] = boff;
            off += s_cnt[g];
            boff += (s_cnt[g] + 63) >> 6;
        }
        s_goff[9] = off; goff[9] = off;
        s_bstart[9] = boff;
        for (int g = 0; g < 9; ++g) gsc[g] = 0;
    }
    __syncthreads();
    for (int b = tid; b < nblk_max; b += blockDim.x) {
        int band = -1, loc = 0;
        for (int g = 0; g < 9; ++g)
            if (b >= s_bstart[g] && b < s_bstart[g + 1]) { band = g; loc = b - s_bstart[g]; }
        blk_band[b] = band;
        if (band >= 0) {
            blk_start[b] = s_goff[band] + loc * 64;
            int rem = s_cnt[band] - loc * 64;
            blk_nrows[b] = rem < 64 ? rem : 64;
        } else { blk_start[b] = 0; blk_nrows[b] = 0; }
    }
}

// ---------------- counting-sort scatter (band sidecar: 0.26 MB vs 18 MB of x) ----------------
__global__ void k_scatter(const u8* __restrict__ bands, const int* __restrict__ goff,
                          int* __restrict__ gsc, int* __restrict__ perm, int B)
{
    __shared__ int wcnt[4][9];
    __shared__ int wpre[4][9];
    __shared__ int gbase[9];
    int tid = threadIdx.x;
    int lane = tid & 63, wave = tid >> 6;
    int i = blockIdx.x * blockDim.x + tid;
    int band = -1, rank = 0;
    if (i < B) band = (int)bands[i];
    for (int k = 0; k < 9; ++k) {
        unsigned long long m = __ballot(band == k);
        if (band == k) rank = __popcll(m & ((1ull << lane) - 1ull));
        if (lane == 0) wcnt[wave][k] = __popcll(m);
    }
    __syncthreads();
    if (tid < 9) {
        int k = tid, run = 0;
        for (int w = 0; w < 4; ++w) { wpre[w][k] = run; run += wcnt[w][k]; }
        gbase[k] = (run > 0) ? atomicAdd(&gsc[k], run) : 0;
    }
    __syncthreads();
    if (i < B && band >= 0) {
        int pos = goff[band] + gbase[band] + wpre[wave][band] + rank;
        perm[pos] = i;
    }
}

// ---------------- fused main kernel: 64 rows / block, 8 waves, uniform band ----------------
// __launch_bounds__(512,4): cap 128 VGPR; compiler lands at 64 naturally (round 5),
// letting HW schedule 8 waves/EU. DO NOT use min-waves=8: round 6 showed it forces
// VGPR=32 -> 931 MB of scratch spill traffic, 224->308 us regression.
// LDS 39,936 B (xA aliased with epilogue reduction scratch) -> 4 blocks/CU.
__global__ __launch_bounds__(512, 4) void k_main(
                       const float* __restrict__ x,
                       const int* __restrict__ perm,
                       const int* __restrict__ blk_band,
                       const int* __restrict__ blk_start,
                       const int* __restrict__ blk_nrows,
                       const u16* __restrict__ W1p, const u16* __restrict__ W2f,
                       const u16* __restrict__ HWf,
                       const u16* __restrict__ SWf, const u16* __restrict__ STWf,
                       const float* __restrict__ tb1, const float* __restrict__ tb2,
                       const float* __restrict__ hb1, const float* __restrict__ hw2,
                       const float* __restrict__ hb2,
                       const float* __restrict__ sb1, const float* __restrict__ sw2,
                       const float* __restrict__ sb2,
                       const float* __restrict__ stb1, const float* __restrict__ stw2,
                       const float* __restrict__ stb2,
                       const float* __restrict__ sp,
                       const float* __restrict__ sun_b1, const float* __restrict__ sun_b2,
                       const float* __restrict__ storm_b1, const float* __restrict__ storm_b2,
                       float* __restrict__ out)
{
    int bb = blk_band[blockIdx.x];
    if (bb < 0) return;
    int rstart = blk_start[blockIdx.x];
    int nrows  = blk_nrows[blockIdx.x];

    // xA dead after A-fragments load (pre-P1); reduction scratch live only in
    // epilogue -> alias (saves 4KB -> 4 blocks/CU).
    __shared__ union {
        u16 xA[64][32];        // 4096 B
        float red[16][64];     // [0:8)=head, [8:12)=sun, [12:16)=storm
    } su;
    __shared__ int rowsL[64];
    __shared__ float sfiL[64], kpL[64];
    __shared__ u16 buf[2][64][136];            // chunk dbuf; aliased as t[64][264]

    int tid = threadIdx.x;
    int lane = tid & 63, wave = tid >> 6;      // wave 0..7
    int quad = lane >> 4, l15 = lane & 15;

    if (tid < 64) {
        int r = rstart + (tid < nrows ? tid : 0);
        rowsL[tid] = perm[r];
    }
    for (int i = tid; i < 64 * 32; i += 512) ((u16*)su.xA)[i] = 0;
    __syncthreads();
    for (int i = tid; i < 64 * 18; i += 512) {
        int r = i / 18, c = i - r * 18;
        float v = x[rowsL[r] * 18 + c];
        if (c < 15) su.xA[r][c] = f2b_hw(v);
        else if (c == 15) sfiL[r] = v;
        else if (c == 16) kpL[r] = v;
    }
    __syncthreads();

    // A-fragments of x: A[m=mt*16+l15][k=quad*8+j]
    bf16x8 ax[4];
#pragma unroll
    for (int mt = 0; mt < 4; ++mt)
        ax[mt] = *(const bf16x8*)&su.xA[mt * 16 + l15][quad * 8];

    f32x4 acc2[2][4] = {};   // [ntl][mt], wave cols = wave*32 + ntl*16

    for (int c = 0; c < 4; ++c) {
        // ---- Phase 1: this wave's 16 cols of chunk c
        f32x4 acc1[4] = {};
        {
            int ncol = c * 128 + wave * 16 + l15;
            bf16x8 bw = *(const bf16x8*)&W1p[ncol * 32 + quad * 8];
#pragma unroll
            for (int mt = 0; mt < 4; ++mt)
                acc1[mt] = MFMA16(ax[mt], bw, acc1[mt]);
        }
        u16 (*bufc)[136] = buf[c & 1];
        {
            int ccol = wave * 16 + l15;
            float bias = tb1[c * 128 + ccol];
#pragma unroll
            for (int mt = 0; mt < 4; ++mt)
#pragma unroll
                for (int r = 0; r < 4; ++r)
                    bufc[mt * 16 + quad * 4 + r][ccol] = f2b_hw(mish_f(acc1[mt][r] + bias));
        }
        __syncthreads();
        // ---- Phase 2 partial: acc2 += chunk @ W2 (this wave's 32 cols), FM loads
        for (int ks = 0; ks < 4; ++ks) {
            bf16x8 a2[4];
#pragma unroll
            for (int mt = 0; mt < 4; ++mt)
                a2[mt] = *(const bf16x8*)&bufc[mt * 16 + l15][ks * 32 + quad * 8];
            int kb = c * 4 + ks;
#pragma unroll
            for (int ntl = 0; ntl < 2; ++ntl) {
                int nt = wave * 2 + ntl;
                bf16x8 bw = *(const bf16x8*)&W2f[((nt * 16 + kb) << 9) + lane * 8];
#pragma unroll
                for (int mt = 0; mt < 4; ++mt)
                    acc2[ntl][mt] = MFMA16(a2[mt], bw, acc2[ntl][mt]);
            }
        }
    }
    __syncthreads();   // all P2 reads of buf done before aliasing with t

    // ---- t = mish(acc2 + tb2) -> LDS t[64][264] (aliases buf)
    u16 (*tmat)[264] = (u16(*)[264])buf;
#pragma unroll
    for (int ntl = 0; ntl < 2; ++ntl) {
        int col = wave * 32 + ntl * 16 + l15;
        float bias = tb2[col];
#pragma unroll
        for (int mt = 0; mt < 4; ++mt)
#pragma unroll
            for (int r = 0; r < 4; ++r)
                tmat[mt * 16 + quad * 4 + r][col] = f2b_hw(mish_f(acc2[ntl][mt][r] + bias));
    }
    __syncthreads();

    // ---- Phase 3: head nt = wave; gates: waves 0-3 sun, 4-7 storm. K=256.
    f32x4 acch[4] = {}, accg[4] = {};
    const u16* Hw = HWf + bb * 32768;
    const u16* Gw = (wave < 4) ? SWf : STWf;
    int gnt = wave & 3;
    for (int kb = 0; kb < 8; ++kb) {
        bf16x8 a3[4];
#pragma unroll
        for (int mt = 0; mt < 4; ++mt)
            a3[mt] = *(const bf16x8*)&tmat[mt * 16 + l15][kb * 32 + quad * 8];
        bf16x8 bh = *(const bf16x8*)&Hw[((wave * 8 + kb) << 9) + lane * 8];
        bf16x8 bg = *(const bf16x8*)&Gw[((gnt * 8 + kb) << 9) + lane * 8];
#pragma unroll
        for (int mt = 0; mt < 4; ++mt) {
            acch[mt] = MFMA16(a3[mt], bh, acch[mt]);
            accg[mt] = MFMA16(a3[mt], bg, accg[mt]);
        }
    }

    // head epilogue: this wave's 16 cols, dot with hw2[band]
    float hsum[4][4];
    {
        int col = wave * 16 + l15;
        float hb = hb1[bb * 128 + col];
        float wv = hw2[bb * 128 + col];
#pragma unroll
        for (int mt = 0; mt < 4; ++mt)
#pragma unroll
            for (int r = 0; r < 4; ++r)
                hsum[mt][r] = mish_f(acch[mt][r] + hb) * wv;
    }
    // gate epilogue: this wave's 16 cols of sun or storm
    float gsum[4][4];
    {
        int n = gnt * 16 + l15;
        float gb = (wave < 4) ? sb1[n] : stb1[n];
        float gw = (wave < 4) ? sw2[n] : stw2[n];
#pragma unroll
        for (int mt = 0; mt < 4; ++mt)
#pragma unroll
            for (int r = 0; r < 4; ++r)
                gsum[mt][r] = mish_f(accg[mt][r] + gb) * gw;
    }
#pragma unroll
    for (int off = 1; off < 16; off <<= 1)
#pragma unroll
        for (int mt = 0; mt < 4; ++mt)
#pragma unroll
            for (int r = 0; r < 4; ++r) {
                hsum[mt][r] += __shfl_xor(hsum[mt][r], off, 64);
                gsum[mt][r] += __shfl_xor(gsum[mt][r], off, 64);
            }
    if (l15 == 0)
#pragma unroll
        for (int mt = 0; mt < 4; ++mt)
#pragma unroll
            for (int r = 0; r < 4; ++r) {
                int row = mt * 16 + quad * 4 + r;
                su.red[wave][row] = hsum[mt][r];
                su.red[8 + wave][row] = gsum[mt][r];   // waves 0-3 -> sun, 4-7 -> storm
            }
    __syncthreads();

    // ---- final scalar math per row (fp32 output)
    if (tid < 64 && tid < nrows) {
        int row = tid;
        float head = hb2[bb];
#pragma unroll
        for (int w = 0; w < 8; ++w) head += su.red[w][row];
        float sl = sb2[0], tl = stb2[0];
#pragma unroll
        for (int w = 0; w < 4; ++w) { sl += su.red[8 + w][row]; tl += su.red[12 + w][row]; }
        float sg = sigmoid_f(sl);
        float tg = sigmoid_f(tl);
        float v1 = sfiL[row], v2 = kpL[row];
        float sun_val = sun_b2[0], storm_val = storm_b2[0];
#pragma unroll
        for (int j = 0; j < 8; ++j) {
            sun_val   += tanh_f(v1 * sp[j]      + sun_b1[j])   * sp[8 + j];
            storm_val += tanh_f(v2 * sp[16 + j] + storm_b1[j]) * sp[24 + j];
        }
        out[rowsL[row]] = head + sg * sun_val + tg * storm_val;
    }
}

// ---------------- fallback: pure-VALU scalar kernel (used if ws too small) ----------------
__global__ __launch_bounds__(64) void k_simple(
    const float* __restrict__ x,
    const float* __restrict__ tw1, const float* __restrict__ tb1,
    const float* __restrict__ tw2, const float* __restrict__ tb2,
    const float* __restrict__ hw1, const float* __restrict__ hb1,
    const float* __restrict__ hw2, const float* __restrict__ hb2,
    const float* __restrict__ sw1, const float* __restrict__ sb1,
    const float* __restrict__ sw2, const float* __restrict__ sb2,
    const float* __restrict__ stw1, const float* __restrict__ stb1,
    const float* __restrict__ stw2, const float* __restrict__ stb2,
    const float* __restrict__ sun_w1, const float* __restrict__ sun_b1,
    const float* __restrict__ sun_w2, const float* __restrict__ sun_b2,
    const float* __restrict__ storm_w1, const float* __restrict__ storm_b1,
    const float* __restrict__ storm_w2, const float* __restrict__ storm_b2,
    float* __restrict__ out)
{
    __shared__ u16 t_lds[256 * 64];

    const int lane = threadIdx.x;
    const int r = blockIdx.x * 64 + lane;

    float xr[15];
#pragma unroll
    for (int k = 0; k < 15; ++k) xr[k] = x[r * 18 + k];
    const float sfi = x[r * 18 + 15];
    const float kp  = x[r * 18 + 16];
    const int band  = (int)x[r * 18 + 17];

    for (int tc = 0; tc < 4; ++tc) {
        float acc[64];
#pragma unroll
        for (int j = 0; j < 64; ++j) acc[j] = 0.0f;
        for (int n = 0; n < 512; ++n) {
            float p = tb1[n];
#pragma unroll
            for (int k = 0; k < 15; ++k) p += xr[k] * tw1[k * 512 + n];
            const float a1n = mish_f(p);
            const float* w2 = &tw2[n * 256 + tc * 64];
#pragma unroll
            for (int j = 0; j < 64; ++j) acc[j] += a1n * w2[j];
        }
#pragma unroll
        for (int j = 0; j < 64; ++j)
            t_lds[(tc * 64 + j) * 64 + lane] = f2b(mish_f(acc[j] + tb2[tc * 64 + j]));
    }
    __syncthreads();

    float head_val = 0.0f;
    for (int g = 0; g < 9; ++g) {
        float hs = 0.0f;
        for (int hc = 0; hc < 2; ++hc) {
            float pre[64];
#pragma unroll
            for (int j = 0; j < 64; ++j) pre[j] = 0.0f;
            for (int d = 0; d < 256; ++d) {
                const float td = b2f(t_lds[d * 64 + lane]);
                const float* wv = &hw1[g * 32768 + d * 128 + hc * 64];
#pragma unroll
                for (int j = 0; j < 64; ++j) pre[j] += td * wv[j];
            }
#pragma unroll
            for (int j = 0; j < 64; ++j) {
                const int h = hc * 64 + j;
                hs += mish_f(pre[j] + hb1[g * 128 + h]) * hw2[g * 128 + h];
            }
        }
        head_val += (band == g) ? (hs + hb2[g]) : 0.0f;
    }

    float pre_s[64], pre_t[64];
#pragma unroll
    for (int j = 0; j < 64; ++j) { pre_s[j] = 0.0f; pre_t[j] = 0.0f; }
    for (int d = 0; d < 256; ++d) {
        const float td = b2f(t_lds[d * 64 + lane]);
        const float* ws1 = &sw1[d * 64];
        const float* wt1 = &stw1[d * 64];
#pragma unroll
        for (int j = 0; j < 64; ++j) {
            pre_s[j] += td * ws1[j];
            pre_t[j] += td * wt1[j];
        }
    }
    float ls = sb2[0], lt = stb2[0];
#pragma unroll
    for (int j = 0; j < 64; ++j) {
        ls += mish_f(pre_s[j] + sb1[j]) * sw2[j];
        lt += mish_f(pre_t[j] + stb1[j]) * stw2[j];
    }
    const float sg = sigmoid_f(ls);
    const float tg = sigmoid_f(lt);

    float sun_val = sun_b2[0], storm_val = storm_b2[0];
#pragma unroll
    for (int j = 0; j < 8; ++j) {
        sun_val   += tanh_f(sfi * splus(sun_w1[j])  + sun_b1[j])   * splus(sun_w2[j]);
        storm_val += tanh_f(kp * splus(storm_w1[j]) + storm_b1[j]) * splus(storm_w2[j]);
    }

    out[r] = head_val + sg * sun_val + tg * storm_val;
}

extern "C" void kernel_launch(void* const* d_in, const int* in_sizes, int n_in,
                              void* d_out, int out_size, void* d_ws, size_t ws_size,
                              hipStream_t stream) {
    (void)n_in; (void)out_size;
    const float* x        = (const float*)d_in[0];
    const float* tw1      = (const float*)d_in[1];
    const float* tb1      = (const float*)d_in[2];
    const float* tw2      = (const float*)d_in[3];
    const float* tb2      = (const float*)d_in[4];
    const float* hw1      = (const float*)d_in[5];
    const float* hb1      = (const float*)d_in[6];
    const float* hw2      = (const float*)d_in[7];
    const float* hb2      = (const float*)d_in[8];
    const float* sw1      = (const float*)d_in[9];
    const float* sb1      = (const float*)d_in[10];
    const float* sw2      = (const float*)d_in[11];
    const float* sb2      = (const float*)d_in[12];
    const float* stw1     = (const float*)d_in[13];
    const float* stb1     = (const float*)d_in[14];
    const float* stw2     = (const float*)d_in[15];
    const float* stb2     = (const float*)d_in[16];
    const float* sun_w1   = (const float*)d_in[17];
    const float* sun_b1   = (const float*)d_in[18];
    const float* sun_w2   = (const float*)d_in[19];
    const float* sun_b2   = (const float*)d_in[20];
    const float* storm_w1 = (const float*)d_in[21];
    const float* storm_b1 = (const float*)d_in[22];
    const float* storm_w2 = (const float*)d_in[23];
    const float* storm_b2 = (const float*)d_in[24];

    const int B = in_sizes[0] / 18;

    if (ws_size < (size_t)WS_NEEDED) {
        k_simple<<<B / 64, 64, 0, stream>>>(x, tw1, tb1, tw2, tb2, hw1, hb1, hw2, hb2,
                                            sw1, sb1, sw2, sb2, stw1, stb1, stw2, stb2,
                                            sun_w1, sun_b1, sun_w2, sun_b2,
                                            storm_w1, storm_b1, storm_w2, storm_b2,
                                            (float*)d_out);
        return;
    }

    char* ws = (char*)d_ws;
    int*   perm      = (int*)(ws + WS_PERM);
    int*   gsc       = (int*)(ws + WS_GSC);
    int*   goff      = (int*)(ws + WS_GOFF);
    int*   blk_band  = (int*)(ws + WS_BBAND);
    int*   blk_start = (int*)(ws + WS_BSTART);
    int*   blk_nrows = (int*)(ws + WS_BNROWS);
    float* sp        = (float*)(ws + WS_SP);
    int*   gpart     = (int*)(ws + WS_GPART);
    u8*    bands     = (u8*)(ws + WS_BANDS);
    u16*   W1p       = (u16*)(ws + WS_W1P);
    u16*   W2f       = (u16*)(ws + WS_W2F);
    u16*   HWf       = (u16*)(ws + WS_HW1F);
    u16*   SWf       = (u16*)(ws + WS_SWF);
    u16*   STWf      = (u16*)(ws + WS_STWF);

    int nblk = B / 64 + 16;

    k_pack<<<PACK_BLOCKS, 256, 0, stream>>>(x, B, tw1, tw2, hw1, sw1, stw1,
                                            sun_w1, sun_w2, storm_w1, storm_w2,
                                            W1p, W2f, HWf, SWf, STWf, sp, gpart, bands);
    k_table<<<1, 256, 0, stream>>>(gpart, goff, gsc, blk_band, blk_start, blk_nrows, nblk);
    k_scatter<<<(B + 255) / 256, 256, 0, stream>>>(bands, goff, gsc, perm, B);
    k_main<<<nblk, 512, 0, stream>>>(x, perm, blk_band, blk_start, blk_nrows,
                                     W1p, W2f, HWf, SWf, STWf,
                                     tb1, tb2, hb1, hw2, hb2,
                                     sb1, sw2, sb2, stb1, stw2, stb2,
                                     sp, sun_b1, sun_b2, storm_b1, storm_b2,
                                     (float*)d_out);
}

// Round 9
// 326.693 us; speedup vs baseline: 1.2593x; 1.0475x over previous
//
#include <hip/hip_runtime.h>
#include <cstdint>

typedef unsigned short u16;
typedef unsigned char u8;
typedef __attribute__((ext_vector_type(8))) __bf16 bf16x8;
typedef __attribute__((ext_vector_type(4))) float f32x4;

#define MFMA16(a, b, c) __builtin_amdgcn_mfma_f32_16x16x32_bf16((a), (b), (c), 0, 0, 0)

__device__ __forceinline__ u16 f2b(float f) {            // SW RNE (prep kernels only)
    union { float f; unsigned u; } v; v.f = f;
    unsigned r = v.u + 0x7fffu + ((v.u >> 16) & 1u);
    return (u16)(r >> 16);
}
__device__ __forceinline__ u16 f2b_hw(float f) {         // HW cvt (hot path)
    union { __bf16 h; u16 u; } cv; cv.h = (__bf16)f; return cv.u;
}
__device__ __forceinline__ float b2f(u16 h) {
    union { unsigned u; float f; } v; v.u = ((unsigned)h) << 16; return v.f;
}
__device__ __forceinline__ float fast_rcp(float x) { return __builtin_amdgcn_rcpf(x); }
// mish(x) = x * tanh(softplus(x)) = x * (u^2-1)/(u^2+1), u = 1+e^x
__device__ __forceinline__ float mish_f(float x) {
    float e = __expf(fminf(x, 40.0f));
    float u = 1.0f + e;
    float u2 = u * u;
    return x * (u2 - 1.0f) * fast_rcp(u2 + 1.0f);
}
__device__ __forceinline__ float tanh_f(float y) {
    float e = __expf(2.0f * y);
    return 1.0f - 2.0f * fast_rcp(e + 1.0f);
}
__device__ __forceinline__ float sigmoid_f(float y) {
    return fast_rcp(1.0f + __expf(-y));
}
__device__ __forceinline__ float splus(float w) { return log1pf(__expf(w)); }

// DPP cross-lane add: v += v[partner]. CTRL must be an integer constant
// expression (builtin requirement -> template parameter, not function arg).
// 1 VALU permute (+1 add) per step, no LDS pipe (round-7 shfl_xor used
// ds_bpermute: ~4 instr + LDS op each; suspected source of the 2e7
// SQ_LDS_BANK_CONFLICT).
template <int CTRL>
__device__ __forceinline__ float dpp_add(float v) {
    union { float f; int i; } s, p;
    s.f = v;
    p.i = __builtin_amdgcn_update_dpp(0, s.i, CTRL, 0xf, 0xf, true);
    return v + p.f;
}
// Sum over each 16-lane row: quad_perm[1,0,3,2]=0xB1 (xor1), quad_perm[2,3,0,1]
// =0x4E (xor2), row_half_mirror=0x141 (merges 4-groups into 8), row_mirror=0x140
// (merges 8-groups into 16). After the 4-group stage the mirrors are exact
// group-sum merges, so the final 16-lane sums are exact.
__device__ __forceinline__ float row16_sum(float v) {
    v = dpp_add<0xB1>(v);
    v = dpp_add<0x4E>(v);
    v = dpp_add<0x141>(v);
    v = dpp_add<0x140>(v);
    return v;
}

// ---------------- workspace layout (bytes) ----------------
#define WS_PERM      0u           // int[262144]
#define WS_GSC       1048576u     // int[16]
#define WS_GOFF      1048640u     // int[16]
#define WS_BBAND     1048704u     // int[4112]
#define WS_BSTART    1065152u     // int[4112]
#define WS_BNROWS    1081600u     // int[4112]
#define WS_SP        1098048u     // float[32]
#define WS_GPART     1098176u     // int[512*9]
#define WS_BANDS     1116608u     // u8[262144] band per row (k_scatter sidecar)
#define WS_W1P       1378752u     // u16[512*32]   [n][k]
#define WS_W2F       1411520u     // u16[256*512]  fragment-major NT=16 KB=16
#define WS_HW1F      1673664u     // u16[9*128*256] fragment-major per band NT=8 KB=8
#define WS_SWF       2263488u     // u16[64*256]   fragment-major NT=4 KB=8
#define WS_STWF      2296256u     // u16[64*256]
#define WS_NEEDED    2329024u

#define PACK_BLOCKS  512

// Fragment-major (FM): tile (nt,kb) -> 1KB block FMbase+((nt*KB+kb)*64+lane)*8,
// lane=(quad*16+l15) holds W[nt*16+l15][kb*32+quad*8+j]. One wave B-load = one
// contiguous coalesced 1KB transaction.

// ---------------- weight packing + band histogram + band sidecar ----------------
__global__ void k_pack(const float* __restrict__ x, int B,
                       const float* __restrict__ tw1, const float* __restrict__ tw2,
                       const float* __restrict__ hw1,
                       const float* __restrict__ sw1, const float* __restrict__ stw1,
                       const float* __restrict__ sun_w1, const float* __restrict__ sun_w2,
                       const float* __restrict__ storm_w1, const float* __restrict__ storm_w2,
                       u16* __restrict__ W1p, u16* __restrict__ W2f, u16* __restrict__ HWf,
                       u16* __restrict__ SWf, u16* __restrict__ STWf,
                       float* __restrict__ sp, int* __restrict__ gpart,
                       u8* __restrict__ bands)
{
    __shared__ int h[9];
    int ltid = threadIdx.x;
    int tid = blockIdx.x * blockDim.x + ltid;
    if (ltid < 9) h[ltid] = 0;
    __syncthreads();
    for (int i = tid; i < B; i += PACK_BLOCKS * 256) {
        int b = (int)x[i * 18 + 17];
        bands[i] = (u8)b;
        atomicAdd(&h[b], 1);
    }

    if (tid < 32) {
        const float* srcs[4] = { sun_w1, sun_w2, storm_w1, storm_w2 };
        float w = srcs[tid >> 3][tid & 7];
        sp[tid] = splus(w);
    }
    const int total = 16384 + 131072 + 294912 + 16384 + 16384;
    for (int i = tid; i < total; i += PACK_BLOCKS * 256) {
        int idx = i;
        if (idx < 16384) {                         // W1p[n][k] : 512 x 32 (k>=15 zero)
            int n = idx >> 5, k = idx & 31;
            W1p[idx] = (k < 15) ? f2b(tw1[k * 512 + n]) : (u16)0;
        } else if ((idx -= 16384) < 131072) {      // W2f: FM NT=16 KB=16
            int tile = idx >> 9, within = idx & 511;
            int lane = within >> 3, j = within & 7;
            int nt = tile >> 4, kb = tile & 15;
            int n = nt * 16 + (lane & 15);
            int k = kb * 32 + (lane >> 4) * 8 + j;
            W2f[idx] = f2b(tw2[k * 256 + n]);
        } else if ((idx -= 131072) < 294912) {     // HWf: per band g, FM NT=8 KB=8
            int g = idx >> 15, r = idx & 32767;
            int tile = r >> 9, within = r & 511;
            int lane = within >> 3, j = within & 7;
            int nt = tile >> 3, kb = tile & 7;
            int n = nt * 16 + (lane & 15);
            int k = kb * 32 + (lane >> 4) * 8 + j;
            HWf[idx] = f2b(hw1[(g * 256 + k) * 128 + n]);
        } else if ((idx -= 294912) < 16384) {      // SWf: FM NT=4 KB=8
            int tile = idx >> 9, within = idx & 511;
            int lane = within >> 3, j = within & 7;
            int nt = tile >> 3, kb = tile & 7;
            int n = nt * 16 + (lane & 15);
            int k = kb * 32 + (lane >> 4) * 8 + j;
            SWf[idx] = f2b(sw1[k * 64 + n]);
        } else {                                   // STWf
            idx -= 16384;
            int tile = idx >> 9, within = idx & 511;
            int lane = within >> 3, j = within & 7;
            int nt = tile >> 3, kb = tile & 7;
            int n = nt * 16 + (lane & 15);
            int k = kb * 32 + (lane >> 4) * 8 + j;
            STWf[idx] = f2b(stw1[k * 64 + n]);
        }
    }
    __syncthreads();
    if (ltid < 9) gpart[blockIdx.x * 9 + ltid] = h[ltid];
}

// ---------------- sum partials, group offsets + per-block table ----------------
__global__ void k_table(const int* __restrict__ gpart, int* __restrict__ goff,
                        int* __restrict__ gsc, int* __restrict__ blk_band,
                        int* __restrict__ blk_start, int* __restrict__ blk_nrows, int nblk_max)
{
    __shared__ int s_goff[10], s_bstart[10], s_cnt[9];
    int tid = threadIdx.x;
    if (tid < 9) {
        int s = 0;
        for (int b = 0; b < PACK_BLOCKS; ++b) s += gpart[b * 9 + tid];
        s_cnt[tid] = s;
    }
    __syncthreads();
    if (tid == 0) {
        int off = 0, boff = 0;
        for (int g = 0; g < 9; ++g) {
            s_goff[g] = off; goff[g] = off;
            s_bstart[g] = boff;
            off += s_cnt[g];
            boff += (s_cnt[g] + 63) >> 6;
        }
        s_goff[9] = off; goff[9] = off;
        s_bstart[9] = boff;
        for (int g = 0; g < 9; ++g) gsc[g] = 0;
    }
    __syncthreads();
    for (int b = tid; b < nblk_max; b += blockDim.x) {
        int band = -1, loc = 0;
        for (int g = 0; g < 9; ++g)
            if (b >= s_bstart[g] && b < s_bstart[g + 1]) { band = g; loc = b - s_bstart[g]; }
        blk_band[b] = band;
        if (band >= 0) {
            blk_start[b] = s_goff[band] + loc * 64;
            int rem = s_cnt[band] - loc * 64;
            blk_nrows[b] = rem < 64 ? rem : 64;
        } else { blk_start[b] = 0; blk_nrows[b] = 0; }
    }
}

// ---------------- counting-sort scatter (band sidecar: 0.26 MB vs 18 MB of x) ----------------
__global__ void k_scatter(const u8* __restrict__ bands, const int* __restrict__ goff,
                          int* __restrict__ gsc, int* __restrict__ perm, int B)
{
    __shared__ int wcnt[4][9];
    __shared__ int wpre[4][9];
    __shared__ int gbase[9];
    int tid = threadIdx.x;
    int lane = tid & 63, wave = tid >> 6;
    int i = blockIdx.x * blockDim.x + tid;
    int band = -1, rank = 0;
    if (i < B) band = (int)bands[i];
    for (int k = 0; k < 9; ++k) {
        unsigned long long m = __ballot(band == k);
        if (band == k) rank = __popcll(m & ((1ull << lane) - 1ull));
        if (lane == 0) wcnt[wave][k] = __popcll(m);
    }
    __syncthreads();
    if (tid < 9) {
        int k = tid, run = 0;
        for (int w = 0; w < 4; ++w) { wpre[w][k] = run; run += wcnt[w][k]; }
        gbase[k] = (run > 0) ? atomicAdd(&gsc[k], run) : 0;
    }
    __syncthreads();
    if (i < B && band >= 0) {
        int pos = goff[band] + gbase[band] + wpre[wave][band] + rank;
        perm[pos] = i;
    }
}

// ---------------- fused main kernel: 64 rows / block, 8 waves, uniform band ----------------
// __launch_bounds__(512,4): cap 128 VGPR; compiler lands at 64 naturally (round 5),
// letting HW schedule up to 8 waves/EU. DO NOT use min-waves=8: round 6 showed it
// forces VGPR=32 -> 931 MB of scratch spill traffic, 224->308 us regression.
// LDS 39,936 B (xA aliased with epilogue reduction scratch) -> 4 blocks/CU.
__global__ __launch_bounds__(512, 4) void k_main(
                       const float* __restrict__ x,
                       const int* __restrict__ perm,
                       const int* __restrict__ blk_band,
                       const int* __restrict__ blk_start,
                       const int* __restrict__ blk_nrows,
                       const u16* __restrict__ W1p, const u16* __restrict__ W2f,
                       const u16* __restrict__ HWf,
                       const u16* __restrict__ SWf, const u16* __restrict__ STWf,
                       const float* __restrict__ tb1, const float* __restrict__ tb2,
                       const float* __restrict__ hb1, const float* __restrict__ hw2,
                       const float* __restrict__ hb2,
                       const float* __restrict__ sb1, const float* __restrict__ sw2,
                       const float* __restrict__ sb2,
                       const float* __restrict__ stb1, const float* __restrict__ stw2,
                       const float* __restrict__ stb2,
                       const float* __restrict__ sp,
                       const float* __restrict__ sun_b1, const float* __restrict__ sun_b2,
                       const float* __restrict__ storm_b1, const float* __restrict__ storm_b2,
                       float* __restrict__ out)
{
    int bb = blk_band[blockIdx.x];
    if (bb < 0) return;
    int rstart = blk_start[blockIdx.x];
    int nrows  = blk_nrows[blockIdx.x];

    // xA dead after A-fragments load (pre-P1); reduction scratch live only in
    // epilogue -> alias (saves 4KB -> 4 blocks/CU).
    __shared__ union {
        u16 xA[64][32];        // 4096 B
        float red[16][64];     // [0:8)=head, [8:12)=sun, [12:16)=storm
    } su;
    __shared__ int rowsL[64];
    __shared__ float sfiL[64], kpL[64];
    __shared__ u16 buf[2][64][136];            // chunk dbuf; aliased as t[64][264]

    int tid = threadIdx.x;
    int lane = tid & 63, wave = tid >> 6;      // wave 0..7
    int quad = lane >> 4, l15 = lane & 15;

    if (tid < 64) {
        int r = rstart + (tid < nrows ? tid : 0);
        rowsL[tid] = perm[r];
    }
    for (int i = tid; i < 64 * 32; i += 512) ((u16*)su.xA)[i] = 0;
    __syncthreads();
    for (int i = tid; i < 64 * 18; i += 512) {
        int r = i / 18, c = i - r * 18;
        float v = x[rowsL[r] * 18 + c];
        if (c < 15) su.xA[r][c] = f2b_hw(v);
        else if (c == 15) sfiL[r] = v;
        else if (c == 16) kpL[r] = v;
    }
    __syncthreads();

    // A-fragments of x: A[m=mt*16+l15][k=quad*8+j]
    bf16x8 ax[4];
#pragma unroll
    for (int mt = 0; mt < 4; ++mt)
        ax[mt] = *(const bf16x8*)&su.xA[mt * 16 + l15][quad * 8];

    f32x4 acc2[2][4] = {};   // [ntl][mt], wave cols = wave*32 + ntl*16

    for (int c = 0; c < 4; ++c) {
        // ---- Phase 1: this wave's 16 cols of chunk c
        f32x4 acc1[4] = {};
        {
            int ncol = c * 128 + wave * 16 + l15;
            bf16x8 bw = *(const bf16x8*)&W1p[ncol * 32 + quad * 8];
#pragma unroll
            for (int mt = 0; mt < 4; ++mt)
                acc1[mt] = MFMA16(ax[mt], bw, acc1[mt]);
        }
        u16 (*bufc)[136] = buf[c & 1];
        {
            int ccol = wave * 16 + l15;
            float bias = tb1[c * 128 + ccol];
#pragma unroll
            for (int mt = 0; mt < 4; ++mt)
#pragma unroll
                for (int r = 0; r < 4; ++r)
                    bufc[mt * 16 + quad * 4 + r][ccol] = f2b_hw(mish_f(acc1[mt][r] + bias));
        }
        __syncthreads();
        // ---- Phase 2 partial: acc2 += chunk @ W2 (this wave's 32 cols), FM loads
        for (int ks = 0; ks < 4; ++ks) {
            bf16x8 a2[4];
#pragma unroll
            for (int mt = 0; mt < 4; ++mt)
                a2[mt] = *(const bf16x8*)&bufc[mt * 16 + l15][ks * 32 + quad * 8];
            int kb = c * 4 + ks;
#pragma unroll
            for (int ntl = 0; ntl < 2; ++ntl) {
                int nt = wave * 2 + ntl;
                bf16x8 bw = *(const bf16x8*)&W2f[((nt * 16 + kb) << 9) + lane * 8];
#pragma unroll
                for (int mt = 0; mt < 4; ++mt)
                    acc2[ntl][mt] = MFMA16(a2[mt], bw, acc2[ntl][mt]);
            }
        }
    }
    __syncthreads();   // all P2 reads of buf done before aliasing with t

    // ---- t = mish(acc2 + tb2) -> LDS t[64][264] (aliases buf)
    u16 (*tmat)[264] = (u16(*)[264])buf;
#pragma unroll
    for (int ntl = 0; ntl < 2; ++ntl) {
        int col = wave * 32 + ntl * 16 + l15;
        float bias = tb2[col];
#pragma unroll
        for (int mt = 0; mt < 4; ++mt)
#pragma unroll
            for (int r = 0; r < 4; ++r)
                tmat[mt * 16 + quad * 4 + r][col] = f2b_hw(mish_f(acc2[ntl][mt][r] + bias));
    }
    __syncthreads();

    // ---- Phase 3: head nt = wave; gates: waves 0-3 sun, 4-7 storm. K=256.
    f32x4 acch[4] = {}, accg[4] = {};
    const u16* Hw = HWf + bb * 32768;
    const u16* Gw = (wave < 4) ? SWf : STWf;
    int gnt = wave & 3;
    for (int kb = 0; kb < 8; ++kb) {
        bf16x8 a3[4];
#pragma unroll
        for (int mt = 0; mt < 4; ++mt)
            a3[mt] = *(const bf16x8*)&tmat[mt * 16 + l15][kb * 32 + quad * 8];
        bf16x8 bh = *(const bf16x8*)&Hw[((wave * 8 + kb) << 9) + lane * 8];
        bf16x8 bg = *(const bf16x8*)&Gw[((gnt * 8 + kb) << 9) + lane * 8];
#pragma unroll
        for (int mt = 0; mt < 4; ++mt) {
            acch[mt] = MFMA16(a3[mt], bh, acch[mt]);
            accg[mt] = MFMA16(a3[mt], bg, accg[mt]);
        }
    }

    // head epilogue: this wave's 16 cols, dot with hw2[band]
    float hsum[4][4];
    {
        int col = wave * 16 + l15;
        float hb = hb1[bb * 128 + col];
        float wv = hw2[bb * 128 + col];
#pragma unroll
        for (int mt = 0; mt < 4; ++mt)
#pragma unroll
            for (int r = 0; r < 4; ++r)
                hsum[mt][r] = mish_f(acch[mt][r] + hb) * wv;
    }
    // gate epilogue: this wave's 16 cols of sun or storm
    float gsum[4][4];
    {
        int n = gnt * 16 + l15;
        float gb = (wave < 4) ? sb1[n] : stb1[n];
        float gw = (wave < 4) ? sw2[n] : stw2[n];
#pragma unroll
        for (int mt = 0; mt < 4; ++mt)
#pragma unroll
            for (int r = 0; r < 4; ++r)
                gsum[mt][r] = mish_f(accg[mt][r] + gb) * gw;
    }
    // DPP cross-lane reduction over the 16 l15-lanes (replaces shfl_xor/ds_bpermute)
#pragma unroll
    for (int mt = 0; mt < 4; ++mt)
#pragma unroll
        for (int r = 0; r < 4; ++r) {
            hsum[mt][r] = row16_sum(hsum[mt][r]);
            gsum[mt][r] = row16_sum(gsum[mt][r]);
        }
    if (l15 == 0)
#pragma unroll
        for (int mt = 0; mt < 4; ++mt)
#pragma unroll
            for (int r = 0; r < 4; ++r) {
                int row = mt * 16 + quad * 4 + r;
                su.red[wave][row] = hsum[mt][r];
                su.red[8 + wave][row] = gsum[mt][r];   // waves 0-3 -> sun, 4-7 -> storm
            }
    __syncthreads();

    // ---- final scalar math per row (fp32 output)
    if (tid < 64 && tid < nrows) {
        int row = tid;
        float head = hb2[bb];
#pragma unroll
        for (int w = 0; w < 8; ++w) head += su.red[w][row];
        float sl = sb2[0], tl = stb2[0];
#pragma unroll
        for (int w = 0; w < 4; ++w) { sl += su.red[8 + w][row]; tl += su.red[12 + w][row]; }
        float sg = sigmoid_f(sl);
        float tg = sigmoid_f(tl);
        float v1 = sfiL[row], v2 = kpL[row];
        float sun_val = sun_b2[0], storm_val = storm_b2[0];
#pragma unroll
        for (int j = 0; j < 8; ++j) {
            sun_val   += tanh_f(v1 * sp[j]      + sun_b1[j])   * sp[8 + j];
            storm_val += tanh_f(v2 * sp[16 + j] + storm_b1[j]) * sp[24 + j];
        }
        out[rowsL[row]] = head + sg * sun_val + tg * storm_val;
    }
}

// ---------------- fallback: pure-VALU scalar kernel (used if ws too small) ----------------
__global__ __launch_bounds__(64) void k_simple(
    const float* __restrict__ x,
    const float* __restrict__ tw1, const float* __restrict__ tb1,
    const float* __restrict__ tw2, const float* __restrict__ tb2,
    const float* __restrict__ hw1, const float* __restrict__ hb1,
    const float* __restrict__ hw2, const float* __restrict__ hb2,
    const float* __restrict__ sw1, const float* __restrict__ sb1,
    const float* __restrict__ sw2, const float* __restrict__ sb2,
    const float* __restrict__ stw1, const float* __restrict__ stb1,
    const float* __restrict__ stw2, const float* __restrict__ stb2,
    const float* __restrict__ sun_w1, const float* __restrict__ sun_b1,
    const float* __restrict__ sun_w2, const float* __restrict__ sun_b2,
    const float* __restrict__ storm_w1, const float* __restrict__ storm_b1,
    const float* __restrict__ storm_w2, const float* __restrict__ storm_b2,
    float* __restrict__ out)
{
    __shared__ u16 t_lds[256 * 64];

    const int lane = threadIdx.x;
    const int r = blockIdx.x * 64 + lane;

    float xr[15];
#pragma unroll
    for (int k = 0; k < 15; ++k) xr[k] = x[r * 18 + k];
    const float sfi = x[r * 18 + 15];
    const float kp  = x[r * 18 + 16];
    const int band  = (int)x[r * 18 + 17];

    for (int tc = 0; tc < 4; ++tc) {
        float acc[64];
#pragma unroll
        for (int j = 0; j < 64; ++j) acc[j] = 0.0f;
        for (int n = 0; n < 512; ++n) {
            float p = tb1[n];
#pragma unroll
            for (int k = 0; k < 15; ++k) p += xr[k] * tw1[k * 512 + n];
            const float a1n = mish_f(p);
            const float* w2 = &tw2[n * 256 + tc * 64];
#pragma unroll
            for (int j = 0; j < 64; ++j) acc[j] += a1n * w2[j];
        }
#pragma unroll
        for (int j = 0; j < 64; ++j)
            t_lds[(tc * 64 + j) * 64 + lane] = f2b(mish_f(acc[j] + tb2[tc * 64 + j]));
    }
    __syncthreads();

    float head_val = 0.0f;
    for (int g = 0; g < 9; ++g) {
        float hs = 0.0f;
        for (int hc = 0; hc < 2; ++hc) {
            float pre[64];
#pragma unroll
            for (int j = 0; j < 64; ++j) pre[j] = 0.0f;
            for (int d = 0; d < 256; ++d) {
                const float td = b2f(t_lds[d * 64 + lane]);
                const float* wv = &hw1[g * 32768 + d * 128 + hc * 64];
#pragma unroll
                for (int j = 0; j < 64; ++j) pre[j] += td * wv[j];
            }
#pragma unroll
            for (int j = 0; j < 64; ++j) {
                const int h = hc * 64 + j;
                hs += mish_f(pre[j] + hb1[g * 128 + h]) * hw2[g * 128 + h];
            }
        }
        head_val += (band == g) ? (hs + hb2[g]) : 0.0f;
    }

    float pre_s[64], pre_t[64];
#pragma unroll
    for (int j = 0; j < 64; ++j) { pre_s[j] = 0.0f; pre_t[j] = 0.0f; }
    for (int d = 0; d < 256; ++d) {
        const float td = b2f(t_lds[d * 64 + lane]);
        const float* ws1 = &sw1[d * 64];
        const float* wt1 = &stw1[d * 64];
#pragma unroll
        for (int j = 0; j < 64; ++j) {
            pre_s[j] += td * ws1[j];
            pre_t[j] += td * wt1[j];
        }
    }
    float ls = sb2[0], lt = stb2[0];
#pragma unroll
    for (int j = 0; j < 64; ++j) {
        ls += mish_f(pre_s[j] + sb1[j]) * sw2[j];
        lt += mish_f(pre_t[j] + stb1[j]) * stw2[j];
    }
    const float sg = sigmoid_f(ls);
    const float tg = sigmoid_f(lt);

    float sun_val = sun_b2[0], storm_val = storm_b2[0];
#pragma unroll
    for (int j = 0; j < 8; ++j) {
        sun_val   += tanh_f(sfi * splus(sun_w1[j])  + sun_b1[j])   * splus(sun_w2[j]);
        storm_val += tanh_f(kp * splus(storm_w1[j]) + storm_b1[j]) * splus(storm_w2[j]);
    }

    out[r] = head_val + sg * sun_val + tg * storm_val;
}

extern "C" void kernel_launch(void* const* d_in, const int* in_sizes, int n_in,
                              void* d_out, int out_size, void* d_ws, size_t ws_size,
                              hipStream_t stream) {
    (void)n_in; (void)out_size;
    const float* x        = (const float*)d_in[0];
    const float* tw1      = (const float*)d_in[1];
    const float* tb1      = (const float*)d_in[2];
    const float* tw2      = (const float*)d_in[3];
    const float* tb2      = (const float*)d_in[4];
    const float* hw1      = (const float*)d_in[5];
    const float* hb1      = (const float*)d_in[6];
    const float* hw2      = (const float*)d_in[7];
    const float* hb2      = (const float*)d_in[8];
    const float* sw1      = (const float*)d_in[9];
    const float* sb1      = (const float*)d_in[10];
    const float* sw2      = (const float*)d_in[11];
    const float* sb2      = (const float*)d_in[12];
    const float* stw1     = (const float*)d_in[13];
    const float* stb1     = (const float*)d_in[14];
    const float* stw2     = (const float*)d_in[15];
    const float* stb2     = (const float*)d_in[16];
    const float* sun_w1   = (const float*)d_in[17];
    const float* sun_b1   = (const float*)d_in[18];
    const float* sun_w2   = (const float*)d_in[19];
    const float* sun_b2   = (const float*)d_in[20];
    const float* storm_w1 = (const float*)d_in[21];
    const float* storm_b1 = (const float*)d_in[22];
    const float* storm_w2 = (const float*)d_in[23];
    const float* storm_b2 = (const float*)d_in[24];

    const int B = in_sizes[0] / 18;

    if (ws_size < (size_t)WS_NEEDED) {
        k_simple<<<B / 64, 64, 0, stream>>>(x, tw1, tb1, tw2, tb2, hw1, hb1, hw2, hb2,
                                            sw1, sb1, sw2, sb2, stw1, stb1, stw2, stb2,
                                            sun_w1, sun_b1, sun_w2, sun_b2,
                                            storm_w1, storm_b1, storm_w2, storm_b2,
                                            (float*)d_out);
        return;
    }

    char* ws = (char*)d_ws;
    int*   perm      = (int*)(ws + WS_PERM);
    int*   gsc       = (int*)(ws + WS_GSC);
    int*   goff      = (int*)(ws + WS_GOFF);
    int*   blk_band  = (int*)(ws + WS_BBAND);
    int*   blk_start = (int*)(ws + WS_BSTART);
    int*   blk_nrows = (int*)(ws + WS_BNROWS);
    float* sp        = (float*)(ws + WS_SP);
    int*   gpart     = (int*)(ws + WS_GPART);
    u8*    bands     = (u8*)(ws + WS_BANDS);
    u16*   W1p       = (u16*)(ws + WS_W1P);
    u16*   W2f       = (u16*)(ws + WS_W2F);
    u16*   HWf       = (u16*)(ws + WS_HW1F);
    u16*   SWf       = (u16*)(ws + WS_SWF);
    u16*   STWf      = (u16*)(ws + WS_STWF);

    int nblk = B / 64 + 16;

    k_pack<<<PACK_BLOCKS, 256, 0, stream>>>(x, B, tw1, tw2, hw1, sw1, stw1,
                                            sun_w1, sun_w2, storm_w1, storm_w2,
                                            W1p, W2f, HWf, SWf, STWf, sp, gpart, bands);
    k_table<<<1, 256, 0, stream>>>(gpart, goff, gsc, blk_band, blk_start, blk_nrows, nblk);
    k_scatter<<<(B + 255) / 256, 256, 0, stream>>>(bands, goff, gsc, perm, B);
    k_main<<<nblk, 512, 0, stream>>>(x, perm, blk_band, blk_start, blk_nrows,
                                     W1p, W2f, HWf, SWf, STWf,
                                     tb1, tb2, hb1, hw2, hb2,
                                     sb1, sw2, sb2, stb1, stw2, stb2,
                                     sp, sun_b1, sun_b2, storm_b1, storm_b2,
                                     (float*)d_out);
}

// Round 10
// 322.018 us; speedup vs baseline: 1.2776x; 1.0145x over previous
//
#include <hip/hip_runtime.h>
#include <cstdint>

typedef unsigned short u16;
typedef unsigned char u8;
typedef __attribute__((ext_vector_type(8))) __bf16 bf16x8;
typedef __attribute__((ext_vector_type(4))) float f32x4;

#define MFMA16(a, b, c) __builtin_amdgcn_mfma_f32_16x16x32_bf16((a), (b), (c), 0, 0, 0)

__device__ __forceinline__ u16 f2b(float f) {            // SW RNE (prep kernels only)
    union { float f; unsigned u; } v; v.f = f;
    unsigned r = v.u + 0x7fffu + ((v.u >> 16) & 1u);
    return (u16)(r >> 16);
}
__device__ __forceinline__ u16 f2b_hw(float f) {         // HW cvt (hot path)
    union { __bf16 h; u16 u; } cv; cv.h = (__bf16)f; return cv.u;
}
__device__ __forceinline__ float b2f(u16 h) {
    union { unsigned u; float f; } v; v.u = ((unsigned)h) << 16; return v.f;
}
__device__ __forceinline__ float fast_rcp(float x) { return __builtin_amdgcn_rcpf(x); }
// mish(x) = x * tanh(softplus(x)); with s=e^x, tanh(softplus) = s(s+2)/(s(s+2)+2)
// (u=1+s; u^2-1 = s(s+2), u^2+1 = s(s+2)+2). One fewer VALU op than the u-form.
__device__ __forceinline__ float mish_f(float x) {
    float s = __expf(fminf(x, 40.0f));
    float p = s * (s + 2.0f);
    return x * p * fast_rcp(p + 2.0f);
}
__device__ __forceinline__ float tanh_f(float y) {
    float e = __expf(2.0f * y);
    return 1.0f - 2.0f * fast_rcp(e + 1.0f);
}
__device__ __forceinline__ float sigmoid_f(float y) {
    return fast_rcp(1.0f + __expf(-y));
}
__device__ __forceinline__ float splus(float w) { return log1pf(__expf(w)); }

// DPP cross-lane add: v += v[partner]. CTRL is a template param (builtin needs ICE).
template <int CTRL>
__device__ __forceinline__ float dpp_add(float v) {
    union { float f; int i; } s, p;
    s.f = v;
    p.i = __builtin_amdgcn_update_dpp(0, s.i, CTRL, 0xf, 0xf, true);
    return v + p.f;
}
// Exact 16-lane-row sum: xor1, xor2, half-mirror (4->8 groups), mirror (8->16).
__device__ __forceinline__ float row16_sum(float v) {
    v = dpp_add<0xB1>(v);
    v = dpp_add<0x4E>(v);
    v = dpp_add<0x141>(v);
    v = dpp_add<0x140>(v);
    return v;
}

// ---------------- workspace layout (bytes) ----------------
#define WS_PERM      0u           // int[262144]
#define WS_GOFF      1048576u     // (unused pad, 64 B)
#define WS_BBAND     1048640u     // int[4112]
#define WS_BSTART    1065088u     // int[4112]
#define WS_BNROWS    1081536u     // int[4112]
#define WS_SP        1097984u     // float[32]
#define WS_GPART     1098112u     // int[512*9]  per-CHUNK band counts
#define WS_CPRE      1116544u     // int[512*9]  exclusive prefix: chunk x band -> perm base
#define WS_BANDS     1134976u     // u8[262144]  band per row
#define WS_W1P       1397120u     // u16[512*32]   [n][k]
#define WS_W2F       1429888u     // u16[256*512]  fragment-major NT=16 KB=16
#define WS_HW1F      1692032u     // u16[9*128*256] fragment-major per band NT=8 KB=8
#define WS_SWF       2281856u     // u16[64*256]   fragment-major NT=4 KB=8
#define WS_STWF      2314624u     // u16[64*256]
#define WS_NEEDED    2347392u

#define PACK_BLOCKS  512

// Fragment-major (FM): tile (nt,kb) -> 1KB block FMbase+((nt*KB+kb)*64+lane)*8,
// lane=(quad*16+l15) holds W[nt*16+l15][kb*32+quad*8+j]. One wave B-load = one
// contiguous coalesced 1KB transaction.

// ---------------- weight packing + PER-CHUNK band histogram + band sidecar ----------------
// Chunked histogram (chunk c = rows [c*CH,(c+1)*CH)) enables an atomic-free
// scatter: k_table turns gpart into exclusive prefixes (cpre), k_scatter derives
// deterministic positions. Round-9 suspect: 9216 same-line global atomics in the
// old k_scatter serializing at L2 (~50-130 us hidden in an unprofiled dispatch).
__global__ void k_pack(const float* __restrict__ x, int B,
                       const float* __restrict__ tw1, const float* __restrict__ tw2,
                       const float* __restrict__ hw1,
                       const float* __restrict__ sw1, const float* __restrict__ stw1,
                       const float* __restrict__ sun_w1, const float* __restrict__ sun_w2,
                       const float* __restrict__ storm_w1, const float* __restrict__ storm_w2,
                       u16* __restrict__ W1p, u16* __restrict__ W2f, u16* __restrict__ HWf,
                       u16* __restrict__ SWf, u16* __restrict__ STWf,
                       float* __restrict__ sp, int* __restrict__ gpart,
                       u8* __restrict__ bands)
{
    __shared__ int h[9];
    int ltid = threadIdx.x;
    int tid = blockIdx.x * blockDim.x + ltid;
    if (ltid < 9) h[ltid] = 0;
    __syncthreads();
    const int CH = B / PACK_BLOCKS;            // 512 rows per chunk
    const int base = blockIdx.x * CH;
    for (int i = ltid; i < CH; i += 256) {
        int r = base + i;
        int b = (int)x[r * 18 + 17];
        bands[r] = (u8)b;
        atomicAdd(&h[b], 1);                   // LDS atomic only
    }

    if (tid < 32) {
        const float* srcs[4] = { sun_w1, sun_w2, storm_w1, storm_w2 };
        float w = srcs[tid >> 3][tid & 7];
        sp[tid] = splus(w);
    }
    const int total = 16384 + 131072 + 294912 + 16384 + 16384;
    for (int i = tid; i < total; i += PACK_BLOCKS * 256) {
        int idx = i;
        if (idx < 16384) {                         // W1p[n][k] : 512 x 32 (k>=15 zero)
            int n = idx >> 5, k = idx & 31;
            W1p[idx] = (k < 15) ? f2b(tw1[k * 512 + n]) : (u16)0;
        } else if ((idx -= 16384) < 131072) {      // W2f: FM NT=16 KB=16
            int tile = idx >> 9, within = idx & 511;
            int lane = within >> 3, j = within & 7;
            int nt = tile >> 4, kb = tile & 15;
            int n = nt * 16 + (lane & 15);
            int k = kb * 32 + (lane >> 4) * 8 + j;
            W2f[idx] = f2b(tw2[k * 256 + n]);
        } else if ((idx -= 131072) < 294912) {     // HWf: per band g, FM NT=8 KB=8
            int g = idx >> 15, r = idx & 32767;
            int tile = r >> 9, within = r & 511;
            int lane = within >> 3, j = within & 7;
            int nt = tile >> 3, kb = tile & 7;
            int n = nt * 16 + (lane & 15);
            int k = kb * 32 + (lane >> 4) * 8 + j;
            HWf[idx] = f2b(hw1[(g * 256 + k) * 128 + n]);
        } else if ((idx -= 294912) < 16384) {      // SWf: FM NT=4 KB=8
            int tile = idx >> 9, within = idx & 511;
            int lane = within >> 3, j = within & 7;
            int nt = tile >> 3, kb = tile & 7;
            int n = nt * 16 + (lane & 15);
            int k = kb * 32 + (lane >> 4) * 8 + j;
            SWf[idx] = f2b(sw1[k * 64 + n]);
        } else {                                   // STWf
            idx -= 16384;
            int tile = idx >> 9, within = idx & 511;
            int lane = within >> 3, j = within & 7;
            int nt = tile >> 3, kb = tile & 7;
            int n = nt * 16 + (lane & 15);
            int k = kb * 32 + (lane >> 4) * 8 + j;
            STWf[idx] = f2b(stw1[k * 64 + n]);
        }
    }
    __syncthreads();
    if (ltid < 9) gpart[blockIdx.x * 9 + ltid] = h[ltid];
}

// ---------------- totals, chunk-prefix table, per-block table ----------------
__global__ void k_table(const int* __restrict__ gpart, int* __restrict__ cpre,
                        int* __restrict__ blk_band,
                        int* __restrict__ blk_start, int* __restrict__ blk_nrows, int nblk_max)
{
    __shared__ int s_goff[10], s_bstart[10], s_cnt[9];
    int tid = threadIdx.x;
    if (tid < 9) {
        int s = 0;
        for (int c = 0; c < PACK_BLOCKS; ++c) s += gpart[c * 9 + tid];
        s_cnt[tid] = s;
    }
    __syncthreads();
    if (tid == 0) {
        int off = 0, boff = 0;
        for (int g = 0; g < 9; ++g) {
            s_goff[g] = off;
            s_bstart[g] = boff;
            off += s_cnt[g];
            boff += (s_cnt[g] + 63) >> 6;
        }
        s_goff[9] = off;
        s_bstart[9] = boff;
    }
    __syncthreads();
    if (tid < 9) {                               // exclusive prefix over chunks
        int run = s_goff[tid];
        for (int c = 0; c < PACK_BLOCKS; ++c) {
            cpre[c * 9 + tid] = run;
            run += gpart[c * 9 + tid];
        }
    }
    for (int b = tid; b < nblk_max; b += blockDim.x) {
        int band = -1, loc = 0;
        for (int g = 0; g < 9; ++g)
            if (b >= s_bstart[g] && b < s_bstart[g + 1]) { band = g; loc = b - s_bstart[g]; }
        blk_band[b] = band;
        if (band >= 0) {
            blk_start[b] = s_goff[band] + loc * 64;
            int rem = s_cnt[band] - loc * 64;
            blk_nrows[b] = rem < 64 ? rem : 64;
        } else { blk_start[b] = 0; blk_nrows[b] = 0; }
    }
}

// ---------------- atomic-free counting-sort scatter ----------------
// Block cid handles chunk rows [cid*512, cid*512+512), one row per thread.
// pos = cpre[cid][band] + (prefix of earlier waves' counts) + (lane rank).
__global__ __launch_bounds__(512) void k_scatter(const u8* __restrict__ bands,
                                                 const int* __restrict__ cpre,
                                                 int* __restrict__ perm, int B)
{
    __shared__ int wcnt[8][9];
    __shared__ int wpre[8][9];
    int tid = threadIdx.x;
    int lane = tid & 63, wave = tid >> 6;
    int i = blockIdx.x * 512 + tid;
    int band = -1, rank = 0;
    if (i < B) band = (int)bands[i];
    for (int k = 0; k < 9; ++k) {
        unsigned long long m = __ballot(band == k);
        if (band == k) rank = __popcll(m & ((1ull << lane) - 1ull));
        if (lane == 0) wcnt[wave][k] = __popcll(m);
    }
    __syncthreads();
    if (tid < 9) {
        int run = 0;
        for (int w = 0; w < 8; ++w) { wpre[w][tid] = run; run += wcnt[w][tid]; }
    }
    __syncthreads();
    if (i < B && band >= 0)
        perm[cpre[blockIdx.x * 9 + band] + wpre[wave][band] + rank] = i;
}

// ---------------- fused main kernel: 64 rows / block, 8 waves, uniform band ----------------
// __launch_bounds__(512,4): cap 128 VGPR; compiler lands at 64 naturally (round 5),
// letting HW schedule up to 8 waves/EU. DO NOT use min-waves=8: round 6 showed it
// forces VGPR=32 -> 931 MB of scratch spill traffic, 224->308 us regression.
// LDS 39,936 B (xA aliased with epilogue reduction scratch) -> 4 blocks/CU.
__global__ __launch_bounds__(512, 4) void k_main(
                       const float* __restrict__ x,
                       const int* __restrict__ perm,
                       const int* __restrict__ blk_band,
                       const int* __restrict__ blk_start,
                       const int* __restrict__ blk_nrows,
                       const u16* __restrict__ W1p, const u16* __restrict__ W2f,
                       const u16* __restrict__ HWf,
                       const u16* __restrict__ SWf, const u16* __restrict__ STWf,
                       const float* __restrict__ tb1, const float* __restrict__ tb2,
                       const float* __restrict__ hb1, const float* __restrict__ hw2,
                       const float* __restrict__ hb2,
                       const float* __restrict__ sb1, const float* __restrict__ sw2,
                       const float* __restrict__ sb2,
                       const float* __restrict__ stb1, const float* __restrict__ stw2,
                       const float* __restrict__ stb2,
                       const float* __restrict__ sp,
                       const float* __restrict__ sun_b1, const float* __restrict__ sun_b2,
                       const float* __restrict__ storm_b1, const float* __restrict__ storm_b2,
                       float* __restrict__ out)
{
    int bb = blk_band[blockIdx.x];
    if (bb < 0) return;
    int rstart = blk_start[blockIdx.x];
    int nrows  = blk_nrows[blockIdx.x];

    __shared__ union {
        u16 xA[64][32];        // 4096 B (dead after A-frag load)
        float red[16][64];     // epilogue: [0:8)=head, [8:12)=sun, [12:16)=storm
    } su;
    __shared__ int rowsL[64];
    __shared__ float sfiL[64], kpL[64];
    __shared__ u16 buf[2][64][136];            // chunk dbuf; aliased as t[64][264]

    int tid = threadIdx.x;
    int lane = tid & 63, wave = tid >> 6;      // wave 0..7
    int quad = lane >> 4, l15 = lane & 15;

    if (tid < 64) {
        int r = rstart + (tid < nrows ? tid : 0);
        rowsL[tid] = perm[r];
    }
    for (int i = tid; i < 64 * 32; i += 512) ((u16*)su.xA)[i] = 0;
    __syncthreads();
    for (int i = tid; i < 64 * 18; i += 512) {
        int r = i / 18, c = i - r * 18;
        float v = x[rowsL[r] * 18 + c];
        if (c < 15) su.xA[r][c] = f2b_hw(v);
        else if (c == 15) sfiL[r] = v;
        else if (c == 16) kpL[r] = v;
    }
    __syncthreads();

    // A-fragments of x: A[m=mt*16+l15][k=quad*8+j]
    bf16x8 ax[4];
#pragma unroll
    for (int mt = 0; mt < 4; ++mt)
        ax[mt] = *(const bf16x8*)&su.xA[mt * 16 + l15][quad * 8];

    f32x4 acc2[2][4] = {};   // [ntl][mt], wave cols = wave*32 + ntl*16

    for (int c = 0; c < 4; ++c) {
        // ---- Phase 1: this wave's 16 cols of chunk c
        f32x4 acc1[4] = {};
        {
            int ncol = c * 128 + wave * 16 + l15;
            bf16x8 bw = *(const bf16x8*)&W1p[ncol * 32 + quad * 8];
#pragma unroll
            for (int mt = 0; mt < 4; ++mt)
                acc1[mt] = MFMA16(ax[mt], bw, acc1[mt]);
        }
        u16 (*bufc)[136] = buf[c & 1];
        {
            int ccol = wave * 16 + l15;
            float bias = tb1[c * 128 + ccol];
#pragma unroll
            for (int mt = 0; mt < 4; ++mt)
#pragma unroll
                for (int r = 0; r < 4; ++r)
                    bufc[mt * 16 + quad * 4 + r][ccol] = f2b_hw(mish_f(acc1[mt][r] + bias));
        }
        __syncthreads();
        // ---- Phase 2 partial: acc2 += chunk @ W2 (this wave's 32 cols), FM loads
        for (int ks = 0; ks < 4; ++ks) {
            bf16x8 a2[4];
#pragma unroll
            for (int mt = 0; mt < 4; ++mt)
                a2[mt] = *(const bf16x8*)&bufc[mt * 16 + l15][ks * 32 + quad * 8];
            int kb = c * 4 + ks;
#pragma unroll
            for (int ntl = 0; ntl < 2; ++ntl) {
                int nt = wave * 2 + ntl;
                bf16x8 bw = *(const bf16x8*)&W2f[((nt * 16 + kb) << 9) + lane * 8];
#pragma unroll
                for (int mt = 0; mt < 4; ++mt)
                    acc2[ntl][mt] = MFMA16(a2[mt], bw, acc2[ntl][mt]);
            }
        }
    }
    __syncthreads();   // all P2 reads of buf done before aliasing with t

    // ---- t = mish(acc2 + tb2) -> LDS t[64][264] (aliases buf)
    u16 (*tmat)[264] = (u16(*)[264])buf;
#pragma unroll
    for (int ntl = 0; ntl < 2; ++ntl) {
        int col = wave * 32 + ntl * 16 + l15;
        float bias = tb2[col];
#pragma unroll
        for (int mt = 0; mt < 4; ++mt)
#pragma unroll
            for (int r = 0; r < 4; ++r)
                tmat[mt * 16 + quad * 4 + r][col] = f2b_hw(mish_f(acc2[ntl][mt][r] + bias));
    }
    __syncthreads();

    // ---- Phase 3: head nt = wave; gates: waves 0-3 sun, 4-7 storm. K=256.
    f32x4 acch[4] = {}, accg[4] = {};
    const u16* Hw = HWf + bb * 32768;
    const u16* Gw = (wave < 4) ? SWf : STWf;
    int gnt = wave & 3;
    for (int kb = 0; kb < 8; ++kb) {
        bf16x8 a3[4];
#pragma unroll
        for (int mt = 0; mt < 4; ++mt)
            a3[mt] = *(const bf16x8*)&tmat[mt * 16 + l15][kb * 32 + quad * 8];
        bf16x8 bh = *(const bf16x8*)&Hw[((wave * 8 + kb) << 9) + lane * 8];
        bf16x8 bg = *(const bf16x8*)&Gw[((gnt * 8 + kb) << 9) + lane * 8];
#pragma unroll
        for (int mt = 0; mt < 4; ++mt) {
            acch[mt] = MFMA16(a3[mt], bh, acch[mt]);
            accg[mt] = MFMA16(a3[mt], bg, accg[mt]);
        }
    }

    // head epilogue: this wave's 16 cols, dot with hw2[band]
    float hsum[4][4];
    {
        int col = wave * 16 + l15;
        float hb = hb1[bb * 128 + col];
        float wv = hw2[bb * 128 + col];
#pragma unroll
        for (int mt = 0; mt < 4; ++mt)
#pragma unroll
            for (int r = 0; r < 4; ++r)
                hsum[mt][r] = mish_f(acch[mt][r] + hb) * wv;
    }
    // gate epilogue: this wave's 16 cols of sun or storm
    float gsum[4][4];
    {
        int n = gnt * 16 + l15;
        float gb = (wave < 4) ? sb1[n] : stb1[n];
        float gw = (wave < 4) ? sw2[n] : stw2[n];
#pragma unroll
        for (int mt = 0; mt < 4; ++mt)
#pragma unroll
            for (int r = 0; r < 4; ++r)
                gsum[mt][r] = mish_f(accg[mt][r] + gb) * gw;
    }
#pragma unroll
    for (int mt = 0; mt < 4; ++mt)
#pragma unroll
        for (int r = 0; r < 4; ++r) {
            hsum[mt][r] = row16_sum(hsum[mt][r]);
            gsum[mt][r] = row16_sum(gsum[mt][r]);
        }
    if (l15 == 0)
#pragma unroll
        for (int mt = 0; mt < 4; ++mt)
#pragma unroll
            for (int r = 0; r < 4; ++r) {
                int row = mt * 16 + quad * 4 + r;
                su.red[wave][row] = hsum[mt][r];
                su.red[8 + wave][row] = gsum[mt][r];   // waves 0-3 -> sun, 4-7 -> storm
            }
    __syncthreads();

    // ---- final scalar math per row (fp32 output)
    if (tid < 64 && tid < nrows) {
        int row = tid;
        float head = hb2[bb];
#pragma unroll
        for (int w = 0; w < 8; ++w) head += su.red[w][row];
        float sl = sb2[0], tl = stb2[0];
#pragma unroll
        for (int w = 0; w < 4; ++w) { sl += su.red[8 + w][row]; tl += su.red[12 + w][row]; }
        float sg = sigmoid_f(sl);
        float tg = sigmoid_f(tl);
        float v1 = sfiL[row], v2 = kpL[row];
        float sun_val = sun_b2[0], storm_val = storm_b2[0];
#pragma unroll
        for (int j = 0; j < 8; ++j) {
            sun_val   += tanh_f(v1 * sp[j]      + sun_b1[j])   * sp[8 + j];
            storm_val += tanh_f(v2 * sp[16 + j] + storm_b1[j]) * sp[24 + j];
        }
        out[rowsL[row]] = head + sg * sun_val + tg * storm_val;
    }
}

// ---------------- fallback: pure-VALU scalar kernel (used if ws too small) ----------------
__global__ __launch_bounds__(64) void k_simple(
    const float* __restrict__ x,
    const float* __restrict__ tw1, const float* __restrict__ tb1,
    const float* __restrict__ tw2, const float* __restrict__ tb2,
    const float* __restrict__ hw1, const float* __restrict__ hb1,
    const float* __restrict__ hw2, const float* __restrict__ hb2,
    const float* __restrict__ sw1, const float* __restrict__ sb1,
    const float* __restrict__ sw2, const float* __restrict__ sb2,
    const float* __restrict__ stw1, const float* __restrict__ stb1,
    const float* __restrict__ stw2, const float* __restrict__ stb2,
    const float* __restrict__ sun_w1, const float* __restrict__ sun_b1,
    const float* __restrict__ sun_w2, const float* __restrict__ sun_b2,
    const float* __restrict__ storm_w1, const float* __restrict__ storm_b1,
    const float* __restrict__ storm_w2, const float* __restrict__ storm_b2,
    float* __restrict__ out)
{
    __shared__ u16 t_lds[256 * 64];

    const int lane = threadIdx.x;
    const int r = blockIdx.x * 64 + lane;

    float xr[15];
#pragma unroll
    for (int k = 0; k < 15; ++k) xr[k] = x[r * 18 + k];
    const float sfi = x[r * 18 + 15];
    const float kp  = x[r * 18 + 16];
    const int band  = (int)x[r * 18 + 17];

    for (int tc = 0; tc < 4; ++tc) {
        float acc[64];
#pragma unroll
        for (int j = 0; j < 64; ++j) acc[j] = 0.0f;
        for (int n = 0; n < 512; ++n) {
            float p = tb1[n];
#pragma unroll
            for (int k = 0; k < 15; ++k) p += xr[k] * tw1[k * 512 + n];
            const float a1n = mish_f(p);
            const float* w2 = &tw2[n * 256 + tc * 64];
#pragma unroll
            for (int j = 0; j < 64; ++j) acc[j] += a1n * w2[j];
        }
#pragma unroll
        for (int j = 0; j < 64; ++j)
            t_lds[(tc * 64 + j) * 64 + lane] = f2b(mish_f(acc[j] + tb2[tc * 64 + j]));
    }
    __syncthreads();

    float head_val = 0.0f;
    for (int g = 0; g < 9; ++g) {
        float hs = 0.0f;
        for (int hc = 0; hc < 2; ++hc) {
            float pre[64];
#pragma unroll
            for (int j = 0; j < 64; ++j) pre[j] = 0.0f;
            for (int d = 0; d < 256; ++d) {
                const float td = b2f(t_lds[d * 64 + lane]);
                const float* wv = &hw1[g * 32768 + d * 128 + hc * 64];
#pragma unroll
                for (int j = 0; j < 64; ++j) pre[j] += td * wv[j];
            }
#pragma unroll
            for (int j = 0; j < 64; ++j) {
                const int h = hc * 64 + j;
                hs += mish_f(pre[j] + hb1[g * 128 + h]) * hw2[g * 128 + h];
            }
        }
        head_val += (band == g) ? (hs + hb2[g]) : 0.0f;
    }

    float pre_s[64], pre_t[64];
#pragma unroll
    for (int j = 0; j < 64; ++j) { pre_s[j] = 0.0f; pre_t[j] = 0.0f; }
    for (int d = 0; d < 256; ++d) {
        const float td = b2f(t_lds[d * 64 + lane]);
        const float* ws1 = &sw1[d * 64];
        const float* wt1 = &stw1[d * 64];
#pragma unroll
        for (int j = 0; j < 64; ++j) {
            pre_s[j] += td * ws1[j];
            pre_t[j] += td * wt1[j];
        }
    }
    float ls = sb2[0], lt = stb2[0];
#pragma unroll
    for (int j = 0; j < 64; ++j) {
        ls += mish_f(pre_s[j] + sb1[j]) * sw2[j];
        lt += mish_f(pre_t[j] + stb1[j]) * stw2[j];
    }
    const float sg = sigmoid_f(ls);
    const float tg = sigmoid_f(lt);

    float sun_val = sun_b2[0], storm_val = storm_b2[0];
#pragma unroll
    for (int j = 0; j < 8; ++j) {
        sun_val   += tanh_f(sfi * splus(sun_w1[j])  + sun_b1[j])   * splus(sun_w2[j]);
        storm_val += tanh_f(kp * splus(storm_w1[j]) + storm_b1[j]) * splus(storm_w2[j]);
    }

    out[r] = head_val + sg * sun_val + tg * storm_val;
}

extern "C" void kernel_launch(void* const* d_in, const int* in_sizes, int n_in,
                              void* d_out, int out_size, void* d_ws, size_t ws_size,
                              hipStream_t stream) {
    (void)n_in; (void)out_size;
    const float* x        = (const float*)d_in[0];
    const float* tw1      = (const float*)d_in[1];
    const float* tb1      = (const float*)d_in[2];
    const float* tw2      = (const float*)d_in[3];
    const float* tb2      = (const float*)d_in[4];
    const float* hw1      = (const float*)d_in[5];
    const float* hb1      = (const float*)d_in[6];
    const float* hw2      = (const float*)d_in[7];
    const float* hb2      = (const float*)d_in[8];
    const float* sw1      = (const float*)d_in[9];
    const float* sb1      = (const float*)d_in[10];
    const float* sw2      = (const float*)d_in[11];
    const float* sb2      = (const float*)d_in[12];
    const float* stw1     = (const float*)d_in[13];
    const float* stb1     = (const float*)d_in[14];
    const float* stw2     = (const float*)d_in[15];
    const float* stb2     = (const float*)d_in[16];
    const float* sun_w1   = (const float*)d_in[17];
    const float* sun_b1   = (const float*)d_in[18];
    const float* sun_w2   = (const float*)d_in[19];
    const float* sun_b2   = (const float*)d_in[20];
    const float* storm_w1 = (const float*)d_in[21];
    const float* storm_b1 = (const float*)d_in[22];
    const float* storm_w2 = (const float*)d_in[23];
    const float* storm_b2 = (const float*)d_in[24];

    const int B = in_sizes[0] / 18;

    if (ws_size < (size_t)WS_NEEDED) {
        k_simple<<<B / 64, 64, 0, stream>>>(x, tw1, tb1, tw2, tb2, hw1, hb1, hw2, hb2,
                                            sw1, sb1, sw2, sb2, stw1, stb1, stw2, stb2,
                                            sun_w1, sun_b1, sun_w2, sun_b2,
                                            storm_w1, storm_b1, storm_w2, storm_b2,
                                            (float*)d_out);
        return;
    }

    char* ws = (char*)d_ws;
    int*   perm      = (int*)(ws + WS_PERM);
    int*   blk_band  = (int*)(ws + WS_BBAND);
    int*   blk_start = (int*)(ws + WS_BSTART);
    int*   blk_nrows = (int*)(ws + WS_BNROWS);
    float* sp        = (float*)(ws + WS_SP);
    int*   gpart     = (int*)(ws + WS_GPART);
    int*   cpre      = (int*)(ws + WS_CPRE);
    u8*    bands     = (u8*)(ws + WS_BANDS);
    u16*   W1p       = (u16*)(ws + WS_W1P);
    u16*   W2f       = (u16*)(ws + WS_W2F);
    u16*   HWf       = (u16*)(ws + WS_HW1F);
    u16*   SWf       = (u16*)(ws + WS_SWF);
    u16*   STWf      = (u16*)(ws + WS_STWF);

    int nblk = B / 64 + 16;

    k_pack<<<PACK_BLOCKS, 256, 0, stream>>>(x, B, tw1, tw2, hw1, sw1, stw1,
                                            sun_w1, sun_w2, storm_w1, storm_w2,
                                            W1p, W2f, HWf, SWf, STWf, sp, gpart, bands);
    k_table<<<1, 256, 0, stream>>>(gpart, cpre, blk_band, blk_start, blk_nrows, nblk);
    k_scatter<<<PACK_BLOCKS, 512, 0, stream>>>(bands, cpre, perm, B);
    k_main<<<nblk, 512, 0, stream>>>(x, perm, blk_band, blk_start, blk_nrows,
                                     W1p, W2f, HWf, SWf, STWf,
                                     tb1, tb2, hb1, hw2, hb2,
                                     sb1, sw2, sb2, stb1, stw2, stb2,
                                     sp, sun_b1, sun_b2, storm_b1, storm_b2,
                                     (float*)d_out);
}